// Round 5
// baseline (390.304 us; speedup 1.0000x reference)
//
#include <hip/hip_runtime.h>
#include <math.h>

typedef __attribute__((ext_vector_type(8))) short bf16x8;
typedef __attribute__((ext_vector_type(4))) float f32x4;

#define CH 512
#define HWP 1024
#define NTOK 1032
#define NTP 1088
#define NPRM 8
#define BB 4
#define EPSV 1e-5f
#define MTOK 4128
#define MPAD 4224
#define QSCL 0.18033688f   // 0.125 * log2(e)
#define LOG2E 1.44269504f

__device__ __forceinline__ float gelu_f(float x) {
  return 0.5f * x * (1.0f + erff(x * 0.70710678118654752440f));
}

__device__ __forceinline__ ushort f2bf(float x) {
  union { float f; unsigned u; } v; v.f = x;
  unsigned r = v.u + 0x7FFF + ((v.u >> 16) & 1);
  return (ushort)(r >> 16);
}

__device__ __forceinline__ float bf2f(ushort u) {
  union { unsigned u; float f; } v; v.u = ((unsigned)u) << 16;
  return v.f;
}

// async global->LDS, 16B/lane. LDS dest wave-uniform base; HW adds lane*16.
// GLOBAL src addr is per-lane -> swizzled layouts via pre-swizzled source.
__device__ __forceinline__ void gl16(const ushort* g, ushort* s) {
  __builtin_amdgcn_global_load_lds(
      (const __attribute__((address_space(1))) unsigned int*)g,
      (__attribute__((address_space(3))) unsigned int*)s,
      16, 0, 0);
}

// ---------------- weight fp32 -> bf16 (packed arena) ----------------
__global__ __launch_bounds__(256) void convw(
    const float* __restrict__ wq, const float* __restrict__ wk, const float* __restrict__ wv,
    const float* __restrict__ wo, const float* __restrict__ w1, const float* __restrict__ w2,
    const float* __restrict__ pgw, const float* __restrict__ opw, const float* __restrict__ gpw,
    ushort* __restrict__ out)
{
  const int total = 2621952;
  for (int i = blockIdx.x * 256 + threadIdx.x; i < total; i += gridDim.x * 256) {
    const float* src; int off;
    if (i < 262144)       { src = wq;  off = i; }
    else if (i < 524288)  { src = wk;  off = i - 262144; }
    else if (i < 786432)  { src = wv;  off = i - 524288; }
    else if (i < 1048576) { src = wo;  off = i - 786432; }
    else if (i < 1572864) { src = w1;  off = i - 1048576; }
    else if (i < 2097152) { src = w2;  off = i - 1572864; }
    else if (i < 2359296) { src = pgw; off = i - 2097152; }
    else if (i < 2621440) { src = opw; off = i - 2359296; }
    else                  { src = gpw; off = i - 2621440; }
    out[i] = f2bf(src[off]);
  }
}

// ---------------- fused dw3x3 + BN + GELU + transpose -> bf16 [b*hw][c] ----------------
__global__ __launch_bounds__(256) void dwt_fused(
    const float* __restrict__ in, const float* __restrict__ w9p,
    const float* __restrict__ bn, ushort* __restrict__ outT)
{
  __shared__ float tile[32][33];
  const int y = blockIdx.x;
  const int c0 = blockIdx.y * 32;
  const int b = blockIdx.z;
  const int tx = threadIdx.x, ty = threadIdx.y;
  #pragma unroll
  for (int i = 0; i < 4; ++i) {
    int c = c0 + ty + i * 8;
    const float* ip = in + ((size_t)(b * CH + c)) * HWP;
    const float* wp = w9p + c * 9;
    float acc = 0.0f;
    #pragma unroll
    for (int dy = 0; dy < 3; ++dy) {
      int yy = y + dy - 1;
      if ((unsigned)yy < 32u) {
        #pragma unroll
        for (int dx = 0; dx < 3; ++dx) {
          int xx = tx + dx - 1;
          if ((unsigned)xx < 32u) acc += ip[yy * 32 + xx] * wp[dy * 3 + dx];
        }
      }
    }
    float g = bn[c], be = bn[CH + c], mm = bn[2 * CH + c], vv = bn[3 * CH + c];
    float s = g * rsqrtf(vv + EPSV);
    tile[ty + i * 8][tx] = gelu_f(acc * s + (be - mm * s));
  }
  __syncthreads();
  #pragma unroll
  for (int i = 0; i < 4; ++i)
    outT[((size_t)(b * HWP + y * 32 + ty + i * 8)) * CH + c0 + tx] = f2bf(tile[tx][ty + i * 8]);
}

// ============ GEMM: 128x128 tile, BK=64, dbuf, coalesced gload_lds + XOR swizzle ============
// LDS tile: [row 0..127][64 bf16] (128B rows). Data at (row, chunk c) holds global
// chunk (c ^ (row&7)) — involution applied at BOTH source addr and ds_read.
__device__ __forceinline__ void stage128(const ushort* pA, const ushort* pB,
                                         ushort* lA, ushort* lB,
                                         int w, int KA, int KB)
{
  #pragma unroll
  for (int j = 0; j < 4; ++j) {
    gl16(pA + (size_t)j * 8 * KA, lA + (w * 32 + j * 8) * 64);
    gl16(pB + (size_t)j * 8 * KB, lB + (w * 32 + j * 8) * 64);
  }
}

__device__ __forceinline__ void comp128(const ushort* lA, const ushort* lB,
                                        int wm, int wn, int l, f32x4 (&acc)[4][4])
{
  #pragma unroll
  for (int ks = 0; ks < 2; ++ks) {
    int kb = ks * 4 + (l >> 4);
    int swz = ((kb ^ (l & 7)) * 8);
    bf16x8 af[4], bfv[4];
    #pragma unroll
    for (int mf = 0; mf < 4; ++mf)
      af[mf] = *(const bf16x8*)(lA + (wm + mf * 16 + (l & 15)) * 64 + swz);
    #pragma unroll
    for (int nf = 0; nf < 4; ++nf)
      bfv[nf] = *(const bf16x8*)(lB + (wn + nf * 16 + (l & 15)) * 64 + swz);
    #pragma unroll
    for (int mf = 0; mf < 4; ++mf) {
      #pragma unroll
      for (int nf = 0; nf < 4; ++nf)
        acc[mf][nf] = __builtin_amdgcn_mfma_f32_16x16x32_bf16(af[mf], bfv[nf], acc[mf][nf], 0, 0, 0);
    }
  }
}

// Abase/Bbase: tile-origin row pointers (A + m0*KA, B + n0*KB)
#define G128_PRE(Abase, Bbase, KA, KB, Kdim) \
  __shared__ ushort sA[2][8192], sB[2][8192]; \
  f32x4 acc[4][4]; \
  { f32x4 z = {0.f, 0.f, 0.f, 0.f}; \
    _Pragma("unroll") for (int i = 0; i < 4; ++i) { _Pragma("unroll") for (int j = 0; j < 4; ++j) acc[i][j] = z; } } \
  const int l = threadIdx.x & 63, w = threadIdx.x >> 6; \
  const int wm = (w >> 1) * 64, wn = (w & 1) * 64; \
  const ushort* pA = (Abase) + (size_t)(w * 32 + (l >> 3)) * (KA) + ((l & 7) ^ (l >> 3)) * 8; \
  const ushort* pB = (Bbase) + (size_t)(w * 32 + (l >> 3)) * (KB) + ((l & 7) ^ (l >> 3)) * 8; \
  stage128(pA, pB, sA[0], sB[0], w, KA, KB); \
  __syncthreads(); \
  const int nk = (Kdim) / 64; \
  for (int kt = 0; kt < nk; ++kt) { \
    if (kt + 1 < nk) \
      stage128(pA + (kt + 1) * 64, pB + (kt + 1) * 64, sA[(kt + 1) & 1], sB[(kt + 1) & 1], w, KA, KB); \
    comp128(sA[kt & 1], sB[kt & 1], wm, wn, l, acc); \
    __syncthreads(); \
  }

// QKV fused: A=xb [MPAD][512], B=wqkv [1536][512]; q scaled by QSCL; v pre-transposed
__global__ __launch_bounds__(256) void gemm_qkv128(
    const ushort* __restrict__ A, const ushort* __restrict__ B,
    ushort* __restrict__ qh, ushort* __restrict__ kh, ushort* __restrict__ vt)
{
  const int n0 = blockIdx.x * 128, m0 = blockIdx.y * 128;
  G128_PRE(A + (size_t)m0 * 512, B + (size_t)n0 * 512, 512, 512, 512)
  #pragma unroll
  for (int nf = 0; nf < 4; ++nf) {
    int n = n0 + wn + nf * 16 + (l & 15);
    #pragma unroll
    for (int mf = 0; mf < 4; ++mf) {
      #pragma unroll
      for (int r = 0; r < 4; ++r) {
        int m = m0 + wm + mf * 16 + (l >> 4) * 4 + r;
        if (m < MTOK) {
          int b = m / NTOK;
          int tok = m - b * NTOK;
          float val = acc[mf][nf][r];
          if (n < 512) {
            qh[((size_t)((b * 8 + (n >> 6)) * NTP) + tok) * 64 + (n & 63)] = f2bf(val * QSCL);
          } else if (n < 1024) {
            int n2 = n - 512;
            kh[((size_t)((b * 8 + (n2 >> 6)) * NTP) + tok) * 64 + (n2 & 63)] = f2bf(val);
          } else {
            int n2 = n - 1024;
            vt[((size_t)((b * 8 + (n2 >> 6)) * 64) + (n2 & 63)) * NTP + tok] = f2bf(val);
          }
        }
      }
    }
  }
}

// residual: jt[m*512+n] += acc + bias
__global__ __launch_bounds__(256) void gemm_res128(
    const ushort* __restrict__ A, const ushort* __restrict__ B,
    float* __restrict__ Cf, const float* __restrict__ bias, int Kdim)
{
  const int n0 = blockIdx.x * 128, m0 = blockIdx.y * 128;
  G128_PRE(A + (size_t)m0 * Kdim, B + (size_t)n0 * Kdim, Kdim, Kdim, Kdim)
  #pragma unroll
  for (int nf = 0; nf < 4; ++nf) {
    int n = n0 + wn + nf * 16 + (l & 15);
    float bv = bias ? bias[n] : 0.0f;
    #pragma unroll
    for (int mf = 0; mf < 4; ++mf) {
      #pragma unroll
      for (int r = 0; r < 4; ++r) {
        int m = m0 + wm + mf * 16 + (l >> 4) * 4 + r;
        if (m < MTOK) Cf[(size_t)m * 512 + n] += acc[mf][nf][r] + bv;
      }
    }
  }
}

// mlp1: bias + gelu -> bf16 [m][1024]
__global__ __launch_bounds__(256) void gemm_gelu128(
    const ushort* __restrict__ A, const ushort* __restrict__ B,
    const float* __restrict__ bias, ushort* __restrict__ Ob)
{
  const int n0 = blockIdx.x * 128, m0 = blockIdx.y * 128;
  G128_PRE(A + (size_t)m0 * 512, B + (size_t)n0 * 512, 512, 512, 512)
  #pragma unroll
  for (int nf = 0; nf < 4; ++nf) {
    int n = n0 + wn + nf * 16 + (l & 15);
    float bv = bias[n];
    #pragma unroll
    for (int mf = 0; mf < 4; ++mf) {
      #pragma unroll
      for (int r = 0; r < 4; ++r) {
        int m = m0 + wm + mf * 16 + (l >> 4) * 4 + r;
        if (m < MTOK) Ob[(size_t)m * 1024 + n] = f2bf(gelu_f(acc[mf][nf][r] + bv));
      }
    }
  }
}

// pointwise conv: A = W[o][c], B = act[b*hw][c]; out f32 [b][o][hw] coalesced.
template<int MODE>
__global__ __launch_bounds__(256) void gemm_pw128(
    const ushort* __restrict__ A, const ushort* __restrict__ B,
    const float* __restrict__ bnp, const float* __restrict__ res, float* __restrict__ Of)
{
  const int hw0 = blockIdx.x * 128, m0 = blockIdx.y * 128;
  const int b = blockIdx.z;
  G128_PRE(A + (size_t)m0 * 512, B + (size_t)(b * HWP + hw0) * 512, 512, 512, 512)
  #pragma unroll
  for (int mf = 0; mf < 4; ++mf) {
    #pragma unroll
    for (int r = 0; r < 4; ++r) {
      int o = m0 + wm + mf * 16 + (l >> 4) * 4 + r;
      float g = bnp[o], be = bnp[CH + o], mm = bnp[2 * CH + o], vv = bnp[3 * CH + o];
      float s = g * rsqrtf(vv + EPSV);
      float sh = be - mm * s;
      #pragma unroll
      for (int nf = 0; nf < 4; ++nf) {
        int hw = hw0 + wn + nf * 16 + (l & 15);
        float x = acc[mf][nf][r] * s + sh;
        size_t oi = ((size_t)(b * CH + o)) * HWP + hw;
        if (MODE == 0) Of[oi] = gelu_f(x);
        else Of[oi] = x + res[oi];
      }
    }
  }
}

// ---------------- pp pooling ([b][c][hw] f32 -> [b*8][c]) ----------------
__global__ __launch_bounds__(128) void pp_pool(const float* __restrict__ pp, float* __restrict__ ppool)
{
  int bc = blockIdx.x;
  int b = bc >> 9, c = bc & 511;
  __shared__ float sums[8];
  if (threadIdx.x < 8) sums[threadIdx.x] = 0.0f;
  __syncthreads();
  const float* ip = pp + (size_t)bc * HWP;
  float s0 = 0.0f, s1 = 0.0f;
  #pragma unroll
  for (int kq = 0; kq < 8; ++kq) {
    float val = ip[threadIdx.x + kq * 128];
    if (kq < 4) s0 += val; else s1 += val;
  }
  int pxr = (threadIdx.x & 31) >> 3;
  atomicAdd(&sums[pxr], s0);
  atomicAdd(&sums[4 + pxr], s1);
  __syncthreads();
  if (threadIdx.x < 8)
    ppool[((size_t)b * 8 + threadIdx.x) * CH + c] = sums[threadIdx.x] * (1.0f / 128.0f);
}

// ---------------- prompt: + embed, LN -> jt rows 0..7 ----------------
__global__ __launch_bounds__(128) void prompt_ln(
    const float* __restrict__ ppool, const float* __restrict__ embed,
    const float* __restrict__ lnp, float* __restrict__ jt)
{
  int rB = blockIdx.x;
  int b = rB >> 3, pI = rB & 7;
  float4 val = ((const float4*)(ppool + (size_t)rB * CH))[threadIdx.x];
  float4 e = ((const float4*)(embed + (size_t)pI * CH))[threadIdx.x];
  val.x += e.x; val.y += e.y; val.z += e.z; val.w += e.w;
  float sum = val.x + val.y + val.z + val.w;
  float sq = val.x * val.x + val.y * val.y + val.z * val.z + val.w * val.w;
  #pragma unroll
  for (int off = 1; off < 64; off <<= 1) { sum += __shfl_xor(sum, off); sq += __shfl_xor(sq, off); }
  __shared__ float s2[4];
  if ((threadIdx.x & 63) == 0) { s2[(threadIdx.x >> 6) * 2] = sum; s2[(threadIdx.x >> 6) * 2 + 1] = sq; }
  __syncthreads();
  sum = s2[0] + s2[2]; sq = s2[1] + s2[3];
  float mu = sum * (1.0f / 512.0f);
  float var = sq * (1.0f / 512.0f) - mu * mu;
  float rstd = rsqrtf(var + EPSV);
  int c = threadIdx.x * 4;
  float4 o;
  o.x = (val.x - mu) * rstd * lnp[c] + lnp[CH + c];
  o.y = (val.y - mu) * rstd * lnp[c + 1] + lnp[CH + c + 1];
  o.z = (val.z - mu) * rstd * lnp[c + 2] + lnp[CH + c + 2];
  o.w = (val.w - mu) * rstd * lnp[c + 3] + lnp[CH + c + 3];
  ((float4*)(jt + ((size_t)(b * NTOK + pI)) * CH))[threadIdx.x] = o;
}

// ---------------- gp 1-chan pw from bf16 [b*hw][c]: row dot ----------------
__global__ __launch_bounds__(256) void gp_dot(
    const ushort* __restrict__ xT, const ushort* __restrict__ wbf,
    const float* __restrict__ b0, float* __restrict__ jdv)
{
  const int b = blockIdx.y;
  const int row0 = blockIdx.x * 16;
  const int l = threadIdx.x & 63, w = threadIdx.x >> 6;
  bf16x8 wv = *(const bf16x8*)(wbf + l * 8);
  float wf[8];
  #pragma unroll
  for (int j = 0; j < 8; ++j) wf[j] = bf2f((ushort)wv[j]);
  #pragma unroll
  for (int rr = 0; rr < 4; ++rr) {
    int hw = row0 + w * 4 + rr;
    bf16x8 xv = *(const bf16x8*)(xT + ((size_t)(b * HWP + hw)) * CH + l * 8);
    float s = 0.0f;
    #pragma unroll
    for (int j = 0; j < 8; ++j) s += wf[j] * bf2f((ushort)xv[j]);
    #pragma unroll
    for (int off = 1; off < 64; off <<= 1) s += __shfl_xor(s, off);
    if (l == 0) jdv[b * NTP + NPRM + hw] = s + b0[0];
  }
}

__global__ __launch_bounds__(256) void jd_pool(float* jd)
{
  int b = blockIdx.x;
  __shared__ float sums[8];
  if (threadIdx.x < 8) sums[threadIdx.x] = 0.0f;
  __syncthreads();
  #pragma unroll
  for (int kq = 0; kq < 4; ++kq) {
    int px = threadIdx.x + kq * 256;
    int y = px >> 5, x = px & 31;
    int r = (y >> 4) * 4 + (x >> 3);
    atomicAdd(&sums[r], jd[b * NTP + NPRM + px]);
  }
  __syncthreads();
  if (threadIdx.x < 8) jd[b * NTP + threadIdx.x] = sums[threadIdx.x] * (1.0f / 128.0f);
}

// ---------------- img tokens transpose ----------------
__global__ __launch_bounds__(256) void img_to_tokens(const float* __restrict__ fused, float* __restrict__ jt)
{
  __shared__ float tile[32][33];
  int hw0 = blockIdx.x * 32, c0 = blockIdx.y * 32, b = blockIdx.z;
  int tx = threadIdx.x, ty = threadIdx.y;
  #pragma unroll
  for (int i = 0; i < 4; ++i)
    tile[ty + i * 8][tx] = fused[((size_t)(b * CH + c0 + ty + i * 8)) * HWP + hw0 + tx];
  __syncthreads();
  #pragma unroll
  for (int i = 0; i < 4; ++i)
    jt[((size_t)(b * NTOK + NPRM + hw0 + ty + i * 8)) * CH + c0 + tx] = tile[tx][ty + i * 8];
}

__global__ __launch_bounds__(256) void tokens_to_img(const float* __restrict__ jt, float* __restrict__ out)
{
  __shared__ float tile[32][33];
  int hw0 = blockIdx.x * 32, c0 = blockIdx.y * 32, b = blockIdx.z;
  int tx = threadIdx.x, ty = threadIdx.y;
  #pragma unroll
  for (int i = 0; i < 4; ++i)
    tile[ty + i * 8][tx] = jt[((size_t)(b * NTOK + NPRM + hw0 + ty + i * 8)) * CH + c0 + tx];
  __syncthreads();
  #pragma unroll
  for (int i = 0; i < 4; ++i)
    out[((size_t)(b * CH + c0 + ty + i * 8)) * HWP + hw0 + tx] = tile[tx][ty + i * 8];
}

// ---------------- row LayerNorm -> bf16 ----------------
__global__ __launch_bounds__(128) void ln_rows_bf(
    const float* __restrict__ in, const float* __restrict__ lnp, ushort* __restrict__ out)
{
  int row = blockIdx.x;
  float4 val = ((const float4*)(in + (size_t)row * CH))[threadIdx.x];
  float sum = val.x + val.y + val.z + val.w;
  float sq = val.x * val.x + val.y * val.y + val.z * val.z + val.w * val.w;
  #pragma unroll
  for (int off = 1; off < 64; off <<= 1) { sum += __shfl_xor(sum, off); sq += __shfl_xor(sq, off); }
  __shared__ float s2[4];
  if ((threadIdx.x & 63) == 0) { s2[(threadIdx.x >> 6) * 2] = sum; s2[(threadIdx.x >> 6) * 2 + 1] = sq; }
  __syncthreads();
  sum = s2[0] + s2[2]; sq = s2[1] + s2[3];
  float mu = sum * (1.0f / 512.0f);
  float var = sq * (1.0f / 512.0f) - mu * mu;
  float rstd = rsqrtf(var + EPSV);
  int c = threadIdx.x * 4;
  ushort4 o;
  o.x = f2bf((val.x - mu) * rstd * lnp[c] + lnp[CH + c]);
  o.y = f2bf((val.y - mu) * rstd * lnp[c + 1] + lnp[CH + c + 1]);
  o.z = f2bf((val.z - mu) * rstd * lnp[c + 2] + lnp[CH + c + 2]);
  o.w = f2bf((val.w - mu) * rstd * lnp[c + 3] + lnp[CH + c + 3]);
  *(ushort4*)(out + (size_t)row * CH + c) = o;
}

// ---------------- MFMA flash attention (exp2 domain), 4 waves, LDS-staged K/V ----------------
__device__ __forceinline__ void tok_coord(int idx, float& y, float& x)
{
  if (idx < NPRM) { y = (float)(idx >> 2); x = (float)(idx & 3) * (1.0f / 3.0f); }
  else { int t = idx - NPRM; y = (float)(t >> 5) * (1.0f / 31.0f); x = (float)(t & 31) * (1.0f / 31.0f); }
}

__global__ __launch_bounds__(256) void attn_mfma2(
    const ushort* __restrict__ qh, const ushort* __restrict__ kh,
    const ushort* __restrict__ vT, const float* __restrict__ jd,
    const float* __restrict__ gw, ushort* __restrict__ ao)
{
  __shared__ ushort sK[8192], sV[8192];
  __shared__ ushort Pl[4][16][72];
  const int t = threadIdx.x, l = t & 63, w = t >> 6;
  const int h = blockIdx.y, b = blockIdx.z;
  const int i0 = blockIdx.x * 64 + w * 16;
  const ushort* Q = qh + (size_t)(b * 8 + h) * NTP * 64;
  const ushort* K = kh + (size_t)(b * 8 + h) * NTP * 64;
  const ushort* V = vT + (size_t)(b * 8 + h) * 64 * NTP;
  const float decay = logf(1.0f - exp2f(-1.0f - 0.5f * (float)h)) * LOG2E;
  const float g0 = gw[0] * decay, g1 = gw[1] * decay;

  bf16x8 qf0 = *(const bf16x8*)(Q + (size_t)(i0 + (l & 15)) * 64 + (l >> 4) * 8);
  bf16x8 qf1 = *(const bf16x8*)(Q + (size_t)(i0 + (l & 15)) * 64 + 32 + (l >> 4) * 8);

  float yi[4], xi[4], jdi[4];
  #pragma unroll
  for (int r = 0; r < 4; ++r) {
    int i = i0 + (l >> 4) * 4 + r;
    tok_coord(i, yi[r], xi[r]);
    jdi[r] = jd[b * NTP + i];
  }

  float m_r[4] = { -1e30f, -1e30f, -1e30f, -1e30f };
  float l_r[4] = { 0.f, 0.f, 0.f, 0.f };
  f32x4 of[4];
  { f32x4 z = {0.f, 0.f, 0.f, 0.f};
    #pragma unroll
    for (int d = 0; d < 4; ++d) of[d] = z; }

#define ASTAGE(buf, j0s) { \
    const ushort* gk = K + (size_t)((j0s) + l) * 64; \
    const ushort* gv = V + (size_t)l * NTP + (j0s); \
    gl16(gk + w * 8,       sK + (buf) * 4096 + w * 512); \
    gl16(gk + (w + 4) * 8, sK + (buf) * 4096 + (w + 4) * 512); \
    gl16(gv + w * 8,       sV + (buf) * 4096 + w * 512); \
    gl16(gv + (w + 4) * 8, sV + (buf) * 4096 + (w + 4) * 512); }

  ASTAGE(0, 0)
  __syncthreads();
  const int NJT = 17;
  for (int jti = 0; jti < NJT; ++jti) {
    const int j0 = jti * 64;
    if (jti + 1 < NJT) ASTAGE((jti + 1) & 1, j0 + 64)
    const ushort* bK = sK + (jti & 1) * 4096;
    const ushort* bV = sV + (jti & 1) * 4096;

    f32x4 sfr[4];
    #pragma unroll
    for (int jf = 0; jf < 4; ++jf) {
      bf16x8 k0 = *(const bf16x8*)(bK + (((l >> 4)) * 64 + jf * 16 + (l & 15)) * 8);
      bf16x8 k1 = *(const bf16x8*)(bK + ((4 + (l >> 4)) * 64 + jf * 16 + (l & 15)) * 8);
      f32x4 z = {0.f, 0.f, 0.f, 0.f};
      z = __builtin_amdgcn_mfma_f32_16x16x32_bf16(qf0, k0, z, 0, 0, 0);
      z = __builtin_amdgcn_mfma_f32_16x16x32_bf16(qf1, k1, z, 0, 0, 0);
      sfr[jf] = z;
    }
    float pvv[4][4];
    float mt[4] = { -1e30f, -1e30f, -1e30f, -1e30f };
    #pragma unroll
    for (int jf = 0; jf < 4; ++jf) {
      int jj = j0 + jf * 16 + (l & 15);
      float yj, xj;
      tok_coord(jj, yj, xj);
      float jdj = jd[b * NTP + jj];
      bool valid = jj < NTOK;
      #pragma unroll
      for (int r = 0; r < 4; ++r) {
        float bias = g0 * (fabsf(yi[r] - yj) + fabsf(xi[r] - xj)) + g1 * fabsf(jdi[r] - jdj);
        float sv = valid ? (sfr[jf][r] + bias) : -1e30f;
        pvv[jf][r] = sv;
        mt[r] = fmaxf(mt[r], sv);
      }
    }
    #pragma unroll
    for (int r = 0; r < 4; ++r) {
      #pragma unroll
      for (int off = 1; off < 16; off <<= 1) mt[r] = fmaxf(mt[r], __shfl_xor(mt[r], off));
    }
    float alpha[4], ls[4];
    #pragma unroll
    for (int r = 0; r < 4; ++r) {
      float mn = fmaxf(m_r[r], mt[r]);
      alpha[r] = exp2f(m_r[r] - mn);
      m_r[r] = mn;
      ls[r] = 0.f;
    }
    #pragma unroll
    for (int jf = 0; jf < 4; ++jf) {
      #pragma unroll
      for (int r = 0; r < 4; ++r) {
        float pp = exp2f(pvv[jf][r] - m_r[r]);
        pvv[jf][r] = pp;
        ls[r] += pp;
      }
    }
    #pragma unroll
    for (int r = 0; r < 4; ++r) {
      #pragma unroll
      for (int off = 1; off < 16; off <<= 1) ls[r] += __shfl_xor(ls[r], off);
      l_r[r] = l_r[r] * alpha[r] + ls[r];
    }
    #pragma unroll
    for (int d = 0; d < 4; ++d) {
      #pragma unroll
      for (int r = 0; r < 4; ++r) of[d][r] *= alpha[r];
    }
    #pragma unroll
    for (int jf = 0; jf < 4; ++jf) {
      #pragma unroll
      for (int r = 0; r < 4; ++r)
        Pl[w][(l >> 4) * 4 + r][jf * 16 + (l & 15)] = f2bf(pvv[jf][r]);
    }
    asm volatile("s_waitcnt lgkmcnt(0)" ::: "memory");
    bf16x8 pa0 = *(const bf16x8*)&Pl[w][l & 15][(l >> 4) * 8];
    bf16x8 pa1 = *(const bf16x8*)&Pl[w][l & 15][32 + (l >> 4) * 8];
    #pragma unroll
    for (int df = 0; df < 4; ++df) {
      bf16x8 v0 = *(const bf16x8*)(bV + (((l >> 4)) * 64 + df * 16 + (l & 15)) * 8);
      bf16x8 v1 = *(const bf16x8*)(bV + ((4 + (l >> 4)) * 64 + df * 16 + (l & 15)) * 8);
      of[df] = __builtin_amdgcn_mfma_f32_16x16x32_bf16(pa0, v0, of[df], 0, 0, 0);
      of[df] = __builtin_amdgcn_mfma_f32_16x16x32_bf16(pa1, v1, of[df], 0, 0, 0);
    }
    __syncthreads();
  }
  #pragma unroll
  for (int r = 0; r < 4; ++r) {
    int i = i0 + (l >> 4) * 4 + r;
    if (i < NTOK) {
      float inv = 1.0f / l_r[r];
      #pragma unroll
      for (int df = 0; df < 4; ++df)
        ao[((size_t)(b * NTOK + i)) * 512 + h * 64 + df * 16 + (l & 15)] = f2bf(of[df][r] * inv);
    }
  }
}

// ---------------- host ----------------
extern "C" void kernel_launch(void* const* d_in, const int* in_sizes, int n_in,
                              void* d_out, int out_size, void* d_ws, size_t ws_size,
                              hipStream_t stream)
{
  const float* fused = (const float*)d_in[0];
  const float* depth = (const float*)d_in[1];
  const float* pg_dw_w = (const float*)d_in[2];
  const float* pg_bn1 = (const float*)d_in[3];
  const float* pg_pw_w = (const float*)d_in[4];
  const float* pg_bn2 = (const float*)d_in[5];
  const float* prompt_embed = (const float*)d_in[6];
  const float* pg_ln = (const float*)d_in[7];
  const float* gp_dw_w = (const float*)d_in[8];
  const float* gp_bn = (const float*)d_in[9];
  const float* gp_pw_w = (const float*)d_in[10];
  const float* gp_pw_b = (const float*)d_in[11];
  const float* gp_weight = (const float*)d_in[12];
  const float* ln1 = (const float*)d_in[13];
  const float* wq = (const float*)d_in[14];
  const float* wk = (const float*)d_in[15];
  const float* wv = (const float*)d_in[16];
  const float* wo = (const float*)d_in[17];
  const float* ln2 = (const float*)d_in[18];
  const float* mlp_w1 = (const float*)d_in[19];
  const float* mlp_b1 = (const float*)d_in[20];
  const float* mlp_w2 = (const float*)d_in[21];
  const float* mlp_b2 = (const float*)d_in[22];
  const float* op_dw_w = (const float*)d_in[23];
  const float* op_bn1 = (const float*)d_in[24];
  const float* op_pw_w = (const float*)d_in[25];
  const float* op_bn2 = (const float*)d_in[26];
  float* out = (float*)d_out;

  char* p = (char*)d_ws;
  auto alloc = [&](size_t bytes) { char* r = p; p += (bytes + 1023) & ~(size_t)1023; return r; };
  float*  jt    = (float*) alloc((size_t)MTOK * 512 * 4);
  ushort* xb    = (ushort*)alloc((size_t)MPAD * 512 * 2);
  ushort* hb    = (ushort*)alloc((size_t)MPAD * 1024 * 2);
  ushort* ao    = (ushort*)alloc((size_t)MPAD * 512 * 2);
  ushort* qhB   = (ushort*)alloc((size_t)32 * NTP * 64 * 2);
  ushort* khB   = (ushort*)alloc((size_t)32 * NTP * 64 * 2);
  ushort* vTB   = (ushort*)alloc((size_t)32 * NTP * 64 * 2);
  ushort* dwT1  = (ushort*)alloc((size_t)BB * HWP * CH * 2);
  ushort* dwT2  = (ushort*)alloc((size_t)BB * HWP * CH * 2);
  float*  ppf   = (float*) alloc((size_t)BB * CH * HWP * 4);
  float*  Bf    = (float*) alloc((size_t)BB * CH * HWP * 4);
  float*  jdv   = (float*) alloc((size_t)BB * NTP * 4);
  float*  ppool = (float*) alloc((size_t)BB * 8 * CH * 4);
  ushort* wbf   = (ushort*)alloc((size_t)2621952 * 2);

  ushort* wqkv_bf = wbf;
  ushort* wo_bf   = wbf + 786432;
  ushort* w1_bf   = wbf + 1048576;
  ushort* w2_bf   = wbf + 1572864;
  ushort* pgw_bf  = wbf + 2097152;
  ushort* opw_bf  = wbf + 2359296;
  ushort* gpw_bf  = wbf + 2621440;

  hipLaunchKernelGGL(convw, dim3(4096), dim3(256), 0, stream,
                     wq, wk, wv, wo, mlp_w1, mlp_w2, pg_pw_w, op_pw_w, gp_pw_w, wbf);

  // --- DepthPromptGenerator ---
  hipLaunchKernelGGL(dwt_fused, dim3(32, 16, BB), dim3(32, 8), 0, stream, depth, pg_dw_w, pg_bn1, dwT1);
  hipLaunchKernelGGL(gemm_pw128<0>, dim3(8, 4, BB), dim3(256), 0, stream, pgw_bf, dwT1, pg_bn2, (const float*)nullptr, ppf);
  hipLaunchKernelGGL(pp_pool, dim3(BB * CH), dim3(128), 0, stream, ppf, ppool);
  hipLaunchKernelGGL(prompt_ln, dim3(BB * NPRM), dim3(128), 0, stream, ppool, prompt_embed, pg_ln, jt);

  // --- GeometryPriorGenerator ---
  hipLaunchKernelGGL(dwt_fused, dim3(32, 16, BB), dim3(32, 8), 0, stream, depth, gp_dw_w, gp_bn, dwT2);
  hipLaunchKernelGGL(gp_dot, dim3(64, BB), dim3(256), 0, stream, dwT2, gpw_bf, gp_pw_b, jdv);
  hipLaunchKernelGGL(jd_pool, dim3(BB), dim3(256), 0, stream, jdv);

  // --- Mixer ---
  hipLaunchKernelGGL(img_to_tokens, dim3(32, 16, BB), dim3(32, 8), 0, stream, fused, jt);
  hipLaunchKernelGGL(ln_rows_bf, dim3(MTOK), dim3(128), 0, stream, jt, ln1, xb);
  hipLaunchKernelGGL(gemm_qkv128, dim3(12, 33), dim3(256), 0, stream, xb, wqkv_bf, qhB, khB, vTB);
  hipLaunchKernelGGL(attn_mfma2, dim3(17, 8, BB), dim3(256), 0, stream, qhB, khB, vTB, jdv, gp_weight, ao);
  hipLaunchKernelGGL(gemm_res128, dim3(4, 33), dim3(256), 0, stream, ao, wo_bf, jt, (const float*)nullptr, 512);
  hipLaunchKernelGGL(ln_rows_bf, dim3(MTOK), dim3(128), 0, stream, jt, ln2, xb);
  hipLaunchKernelGGL(gemm_gelu128, dim3(8, 33), dim3(256), 0, stream, xb, w1_bf, mlp_b1, hb);
  hipLaunchKernelGGL(gemm_res128, dim3(4, 33), dim3(256), 0, stream, hb, w2_bf, jt, mlp_b2, 1024);

  // --- out_proj ---
  hipLaunchKernelGGL(tokens_to_img, dim3(32, 16, BB), dim3(32, 8), 0, stream, jt, Bf);
  hipLaunchKernelGGL(dwt_fused, dim3(32, 16, BB), dim3(32, 8), 0, stream, Bf, op_dw_w, op_bn1, dwT1);
  hipLaunchKernelGGL(gemm_pw128<1>, dim3(8, 4, BB), dim3(256), 0, stream, opw_bf, dwT1, op_bn2, fused, out);
}

// Round 6
// 388.281 us; speedup vs baseline: 1.0052x; 1.0052x over previous
//
#include <hip/hip_runtime.h>
#include <math.h>

typedef __attribute__((ext_vector_type(8))) short bf16x8;
typedef __attribute__((ext_vector_type(4))) float f32x4;

#define CH 512
#define HWP 1024
#define NTOK 1032
#define NTP 1088
#define NPRM 8
#define BB 4
#define EPSV 1e-5f
#define MTOK 4128
#define MPAD 4224
#define QSCL 0.18033688f   // 0.125 * log2(e)
#define LOG2E 1.44269504f

__device__ __forceinline__ float gelu_f(float x) {
  return 0.5f * x * (1.0f + erff(x * 0.70710678118654752440f));
}

__device__ __forceinline__ ushort f2bf(float x) {
  union { float f; unsigned u; } v; v.f = x;
  unsigned r = v.u + 0x7FFF + ((v.u >> 16) & 1);
  return (ushort)(r >> 16);
}

__device__ __forceinline__ float bf2f(ushort u) {
  union { unsigned u; float f; } v; v.u = ((unsigned)u) << 16;
  return v.f;
}

__device__ __forceinline__ void gl16(const ushort* g, ushort* s) {
  __builtin_amdgcn_global_load_lds(
      (const __attribute__((address_space(1))) unsigned int*)g,
      (__attribute__((address_space(3))) unsigned int*)s,
      16, 0, 0);
}

// ---------------- weight fp32 -> bf16 (packed arena) ----------------
__global__ __launch_bounds__(256) void convw(
    const float* __restrict__ wq, const float* __restrict__ wk, const float* __restrict__ wv,
    const float* __restrict__ wo, const float* __restrict__ w1, const float* __restrict__ w2,
    const float* __restrict__ pgw, const float* __restrict__ opw, const float* __restrict__ gpw,
    ushort* __restrict__ out)
{
  const int total = 2621952;
  for (int i = blockIdx.x * 256 + threadIdx.x; i < total; i += gridDim.x * 256) {
    const float* src; int off;
    if (i < 262144)       { src = wq;  off = i; }
    else if (i < 524288)  { src = wk;  off = i - 262144; }
    else if (i < 786432)  { src = wv;  off = i - 524288; }
    else if (i < 1048576) { src = wo;  off = i - 786432; }
    else if (i < 1572864) { src = w1;  off = i - 1048576; }
    else if (i < 2097152) { src = w2;  off = i - 1572864; }
    else if (i < 2359296) { src = pgw; off = i - 2097152; }
    else if (i < 2621440) { src = opw; off = i - 2359296; }
    else                  { src = gpw; off = i - 2621440; }
    out[i] = f2bf(src[off]);
  }
}

// -------- fused DUAL dw3x3 + BN + GELU + transpose -> bf16 [b*hw][c] (pg and gp) --------
__global__ __launch_bounds__(256) void dwt_dual(
    const float* __restrict__ in,
    const float* __restrict__ w1p, const float* __restrict__ bn1,
    const float* __restrict__ w2p, const float* __restrict__ bn2,
    ushort* __restrict__ o1, ushort* __restrict__ o2)
{
  __shared__ float t1[32][33];
  __shared__ float t2[32][33];
  const int y = blockIdx.x;
  const int c0 = blockIdx.y * 32;
  const int b = blockIdx.z;
  const int tx = threadIdx.x, ty = threadIdx.y;
  #pragma unroll
  for (int i = 0; i < 4; ++i) {
    int c = c0 + ty + i * 8;
    const float* ip = in + ((size_t)(b * CH + c)) * HWP;
    const float* wa = w1p + c * 9;
    const float* wb = w2p + c * 9;
    float a1 = 0.0f, a2 = 0.0f;
    #pragma unroll
    for (int dy = 0; dy < 3; ++dy) {
      int yy = y + dy - 1;
      if ((unsigned)yy < 32u) {
        #pragma unroll
        for (int dx = 0; dx < 3; ++dx) {
          int xx = tx + dx - 1;
          if ((unsigned)xx < 32u) {
            float v = ip[yy * 32 + xx];
            a1 += v * wa[dy * 3 + dx];
            a2 += v * wb[dy * 3 + dx];
          }
        }
      }
    }
    float g1 = bn1[c], be1 = bn1[CH + c], m1 = bn1[2 * CH + c], v1 = bn1[3 * CH + c];
    float s1 = g1 * rsqrtf(v1 + EPSV);
    t1[ty + i * 8][tx] = gelu_f(a1 * s1 + (be1 - m1 * s1));
    float g2 = bn2[c], be2 = bn2[CH + c], m2 = bn2[2 * CH + c], v2 = bn2[3 * CH + c];
    float s2 = g2 * rsqrtf(v2 + EPSV);
    t2[ty + i * 8][tx] = gelu_f(a2 * s2 + (be2 - m2 * s2));
  }
  __syncthreads();
  #pragma unroll
  for (int i = 0; i < 4; ++i) {
    size_t row = (size_t)(b * HWP + y * 32 + ty + i * 8) * CH + c0 + tx;
    o1[row] = f2bf(t1[tx][ty + i * 8]);
    o2[row] = f2bf(t2[tx][ty + i * 8]);
  }
}

// ============ GEMM: 128x128 tile, BK=64, dbuf, coalesced gload_lds + XOR swizzle ============
__device__ __forceinline__ void stage128(const ushort* pA, const ushort* pB,
                                         ushort* lA, ushort* lB,
                                         int w, int KA, int KB)
{
  #pragma unroll
  for (int j = 0; j < 4; ++j) {
    gl16(pA + (size_t)j * 8 * KA, lA + (w * 32 + j * 8) * 64);
    gl16(pB + (size_t)j * 8 * KB, lB + (w * 32 + j * 8) * 64);
  }
}

__device__ __forceinline__ void comp128(const ushort* lA, const ushort* lB,
                                        int wm, int wn, int l, f32x4 (&acc)[4][4])
{
  #pragma unroll
  for (int ks = 0; ks < 2; ++ks) {
    int kb = ks * 4 + (l >> 4);
    int swz = ((kb ^ (l & 7)) * 8);
    bf16x8 af[4], bfv[4];
    #pragma unroll
    for (int mf = 0; mf < 4; ++mf)
      af[mf] = *(const bf16x8*)(lA + (wm + mf * 16 + (l & 15)) * 64 + swz);
    #pragma unroll
    for (int nf = 0; nf < 4; ++nf)
      bfv[nf] = *(const bf16x8*)(lB + (wn + nf * 16 + (l & 15)) * 64 + swz);
    #pragma unroll
    for (int mf = 0; mf < 4; ++mf) {
      #pragma unroll
      for (int nf = 0; nf < 4; ++nf)
        acc[mf][nf] = __builtin_amdgcn_mfma_f32_16x16x32_bf16(af[mf], bfv[nf], acc[mf][nf], 0, 0, 0);
    }
  }
}

#define G128_PRE(Abase, Bbase, KA, KB, Kdim) \
  __shared__ ushort sA[2][8192], sB[2][8192]; \
  f32x4 acc[4][4]; \
  { f32x4 z = {0.f, 0.f, 0.f, 0.f}; \
    _Pragma("unroll") for (int i = 0; i < 4; ++i) { _Pragma("unroll") for (int j = 0; j < 4; ++j) acc[i][j] = z; } } \
  const int l = threadIdx.x & 63, w = threadIdx.x >> 6; \
  const int wm = (w >> 1) * 64, wn = (w & 1) * 64; \
  const ushort* pA = (Abase) + (size_t)(w * 32 + (l >> 3)) * (KA) + ((l & 7) ^ (l >> 3)) * 8; \
  const ushort* pB = (Bbase) + (size_t)(w * 32 + (l >> 3)) * (KB) + ((l & 7) ^ (l >> 3)) * 8; \
  stage128(pA, pB, sA[0], sB[0], w, KA, KB); \
  __syncthreads(); \
  const int nk = (Kdim) / 64; \
  for (int kt = 0; kt < nk; ++kt) { \
    if (kt + 1 < nk) \
      stage128(pA + (kt + 1) * 64, pB + (kt + 1) * 64, sA[(kt + 1) & 1], sB[(kt + 1) & 1], w, KA, KB); \
    comp128(sA[kt & 1], sB[kt & 1], wm, wn, l, acc); \
    __syncthreads(); \
  }

// QKV fused
__global__ __launch_bounds__(256) void gemm_qkv128(
    const ushort* __restrict__ A, const ushort* __restrict__ B,
    ushort* __restrict__ qh, ushort* __restrict__ kh, ushort* __restrict__ vt)
{
  const int n0 = blockIdx.x * 128, m0 = blockIdx.y * 128;
  G128_PRE(A + (size_t)m0 * 512, B + (size_t)n0 * 512, 512, 512, 512)
  #pragma unroll
  for (int nf = 0; nf < 4; ++nf) {
    int n = n0 + wn + nf * 16 + (l & 15);
    #pragma unroll
    for (int mf = 0; mf < 4; ++mf) {
      #pragma unroll
      for (int r = 0; r < 4; ++r) {
        int m = m0 + wm + mf * 16 + (l >> 4) * 4 + r;
        if (m < MTOK) {
          int b = m / NTOK;
          int tok = m - b * NTOK;
          float val = acc[mf][nf][r];
          if (n < 512) {
            qh[((size_t)((b * 8 + (n >> 6)) * NTP) + tok) * 64 + (n & 63)] = f2bf(val * QSCL);
          } else if (n < 1024) {
            int n2 = n - 512;
            kh[((size_t)((b * 8 + (n2 >> 6)) * NTP) + tok) * 64 + (n2 & 63)] = f2bf(val);
          } else {
            int n2 = n - 1024;
            vt[((size_t)((b * 8 + (n2 >> 6)) * 64) + (n2 & 63)) * NTP + tok] = f2bf(val);
          }
        }
      }
    }
  }
}

// residual: jt[m*512+n] += acc + bias
__global__ __launch_bounds__(256) void gemm_res128(
    const ushort* __restrict__ A, const ushort* __restrict__ B,
    float* __restrict__ Cf, const float* __restrict__ bias, int Kdim)
{
  const int n0 = blockIdx.x * 128, m0 = blockIdx.y * 128;
  G128_PRE(A + (size_t)m0 * Kdim, B + (size_t)n0 * Kdim, Kdim, Kdim, Kdim)
  #pragma unroll
  for (int nf = 0; nf < 4; ++nf) {
    int n = n0 + wn + nf * 16 + (l & 15);
    float bv = bias ? bias[n] : 0.0f;
    #pragma unroll
    for (int mf = 0; mf < 4; ++mf) {
      #pragma unroll
      for (int r = 0; r < 4; ++r) {
        int m = m0 + wm + mf * 16 + (l >> 4) * 4 + r;
        if (m < MTOK) Cf[(size_t)m * 512 + n] += acc[mf][nf][r] + bv;
      }
    }
  }
}

// mlp1: bias + gelu -> bf16 [m][1024]
__global__ __launch_bounds__(256) void gemm_gelu128(
    const ushort* __restrict__ A, const ushort* __restrict__ B,
    const float* __restrict__ bias, ushort* __restrict__ Ob)
{
  const int n0 = blockIdx.x * 128, m0 = blockIdx.y * 128;
  G128_PRE(A + (size_t)m0 * 512, B + (size_t)n0 * 512, 512, 512, 512)
  #pragma unroll
  for (int nf = 0; nf < 4; ++nf) {
    int n = n0 + wn + nf * 16 + (l & 15);
    float bv = bias[n];
    #pragma unroll
    for (int mf = 0; mf < 4; ++mf) {
      #pragma unroll
      for (int r = 0; r < 4; ++r) {
        int m = m0 + wm + mf * 16 + (l >> 4) * 4 + r;
        if (m < MTOK) Ob[(size_t)m * 1024 + n] = f2bf(gelu_f(acc[mf][nf][r] + bv));
      }
    }
  }
}

// pg pointwise: BN + GELU, pooled ONLY (no full map output). ppool must be pre-zeroed.
__global__ __launch_bounds__(256) void gemm_pw_pool(
    const ushort* __restrict__ A, const ushort* __restrict__ B,
    const float* __restrict__ bnp, float* __restrict__ ppool)
{
  __shared__ float poolL[8][128];
  const int hw0 = blockIdx.x * 128, m0 = blockIdx.y * 128;
  const int b = blockIdx.z;
  {
    int t = threadIdx.x;
    #pragma unroll
    for (int k = 0; k < 4; ++k) { int idx = t + k * 256; poolL[idx >> 7][idx & 127] = 0.0f; }
  }
  G128_PRE(A + (size_t)m0 * 512, B + (size_t)(b * HWP + hw0) * 512, 512, 512, 512)
  #pragma unroll
  for (int mf = 0; mf < 4; ++mf) {
    #pragma unroll
    for (int r = 0; r < 4; ++r) {
      int ol = wm + mf * 16 + (l >> 4) * 4 + r;
      int o = m0 + ol;
      float g = bnp[o], be = bnp[CH + o], mm = bnp[2 * CH + o], vv = bnp[3 * CH + o];
      float s = g * rsqrtf(vv + EPSV);
      float sh = be - mm * s;
      #pragma unroll
      for (int nf = 0; nf < 4; ++nf) {
        int hw = hw0 + wn + nf * 16 + (l & 15);
        float x = gelu_f(acc[mf][nf][r] * s + sh);
        int y = hw >> 5, xx = hw & 31;
        int rg = (y >> 4) * 4 + (xx >> 3);
        atomicAdd(&poolL[rg][ol], x);
      }
    }
  }
  __syncthreads();
  {
    int t = threadIdx.x;
    #pragma unroll
    for (int k = 0; k < 4; ++k) {
      int idx = t + k * 256;
      int rg = idx >> 7, oo = idx & 127;
      float v = poolL[rg][oo];
      if (v != 0.0f)
        atomicAdd(&ppool[((size_t)(b * 8 + rg)) * 512 + m0 + oo], v * (1.0f / 128.0f));
    }
  }
}

// op pointwise: BN + residual add -> out f32 [b][o][hw]
__global__ __launch_bounds__(256) void gemm_pw_res(
    const ushort* __restrict__ A, const ushort* __restrict__ B,
    const float* __restrict__ bnp, const float* __restrict__ res, float* __restrict__ Of)
{
  const int hw0 = blockIdx.x * 128, m0 = blockIdx.y * 128;
  const int b = blockIdx.z;
  G128_PRE(A + (size_t)m0 * 512, B + (size_t)(b * HWP + hw0) * 512, 512, 512, 512)
  #pragma unroll
  for (int mf = 0; mf < 4; ++mf) {
    #pragma unroll
    for (int r = 0; r < 4; ++r) {
      int o = m0 + wm + mf * 16 + (l >> 4) * 4 + r;
      float g = bnp[o], be = bnp[CH + o], mm = bnp[2 * CH + o], vv = bnp[3 * CH + o];
      float s = g * rsqrtf(vv + EPSV);
      float sh = be - mm * s;
      #pragma unroll
      for (int nf = 0; nf < 4; ++nf) {
        int hw = hw0 + wn + nf * 16 + (l & 15);
        size_t oi = ((size_t)(b * CH + o)) * HWP + hw;
        Of[oi] = acc[mf][nf][r] * s + sh + res[oi];
      }
    }
  }
}

// -------- COMBO: img tokenize+LN1 | prompt pg_ln+LN1 | gp dot + region pool --------
__global__ __launch_bounds__(256) void combo_mid(
    const float* __restrict__ fused, const float* __restrict__ ppool,
    const float* __restrict__ embed, const float* __restrict__ pgln,
    const float* __restrict__ ln1, float* __restrict__ jt, ushort* __restrict__ xb,
    const ushort* __restrict__ dwT2, const ushort* __restrict__ gpw,
    const float* __restrict__ b0, float* __restrict__ jdv)
{
  __shared__ float T[32][513];
  __shared__ float red[16];
  const int t = threadIdx.x;
  const int bx = blockIdx.x;
  if (bx < 128) {
    // ---- img tokens: transpose fused -> jt (f32) + LN1 -> xb (bf16) ----
    int b = bx >> 5, hw0 = (bx & 31) * 32;
    int tx = t & 31, ty = t >> 5;
    #pragma unroll
    for (int cc = 0; cc < 512; cc += 8)
      T[tx][cc + ty] = fused[((size_t)(b * 512 + cc + ty)) * 1024 + hw0 + tx];
    __syncthreads();
    int tok = t >> 3, j = t & 7;
    float s = 0.f, sq = 0.f;
    #pragma unroll
    for (int i = 0; i < 64; ++i) {
      float v = T[tok][j * 64 + i];
      s += v; sq += v * v;
    }
    s += __shfl_xor(s, 1); sq += __shfl_xor(sq, 1);
    s += __shfl_xor(s, 2); sq += __shfl_xor(sq, 2);
    s += __shfl_xor(s, 4); sq += __shfl_xor(sq, 4);
    float mu = s * (1.f / 512.f);
    float var = sq * (1.f / 512.f) - mu * mu;
    float rstd = rsqrtf(var + EPSV);
    size_t row = (size_t)(b * NTOK + NPRM + hw0 + tok);
    #pragma unroll
    for (int i = 0; i < 64; i += 4) {
      int c = j * 64 + i;
      float4 v4;
      v4.x = T[tok][c]; v4.y = T[tok][c + 1]; v4.z = T[tok][c + 2]; v4.w = T[tok][c + 3];
      *(float4*)(jt + row * 512 + c) = v4;
      ushort4 u;
      u.x = f2bf((v4.x - mu) * rstd * ln1[c] + ln1[512 + c]);
      u.y = f2bf((v4.y - mu) * rstd * ln1[c + 1] + ln1[512 + c + 1]);
      u.z = f2bf((v4.z - mu) * rstd * ln1[c + 2] + ln1[512 + c + 2]);
      u.w = f2bf((v4.w - mu) * rstd * ln1[c + 3] + ln1[512 + c + 3]);
      *(ushort4*)(xb + row * 512 + c) = u;
    }
  } else if (bx < 160) {
    // ---- prompt tokens: pool+embed -> pg_ln -> jt ; then LN1 -> xb ----
    int idx = bx - 128, b = idx >> 3, pI = idx & 7;
    int c = t * 2;
    float2 v = *(const float2*)(ppool + ((size_t)(b * 8 + pI)) * 512 + c);
    float2 e = *(const float2*)(embed + pI * 512 + c);
    v.x += e.x; v.y += e.y;
    float s = v.x + v.y, sq = v.x * v.x + v.y * v.y;
    #pragma unroll
    for (int off = 1; off < 64; off <<= 1) { s += __shfl_xor(s, off); sq += __shfl_xor(sq, off); }
    if ((t & 63) == 0) { red[(t >> 6) * 2] = s; red[(t >> 6) * 2 + 1] = sq; }
    __syncthreads();
    s = red[0] + red[2] + red[4] + red[6];
    sq = red[1] + red[3] + red[5] + red[7];
    float mu = s * (1.f / 512.f);
    float rstd = rsqrtf(sq * (1.f / 512.f) - mu * mu + EPSV);
    float o0 = (v.x - mu) * rstd * pgln[c] + pgln[512 + c];
    float o1 = (v.y - mu) * rstd * pgln[c + 1] + pgln[512 + c + 1];
    size_t row = (size_t)(b * NTOK + pI);
    jt[row * 512 + c] = o0;
    jt[row * 512 + c + 1] = o1;
    float s2 = o0 + o1, sq2 = o0 * o0 + o1 * o1;
    #pragma unroll
    for (int off = 1; off < 64; off <<= 1) { s2 += __shfl_xor(s2, off); sq2 += __shfl_xor(sq2, off); }
    if ((t & 63) == 0) { red[8 + (t >> 6) * 2] = s2; red[9 + (t >> 6) * 2] = sq2; }
    __syncthreads();
    s2 = red[8] + red[10] + red[12] + red[14];
    sq2 = red[9] + red[11] + red[13] + red[15];
    float mu2 = s2 * (1.f / 512.f);
    float rstd2 = rsqrtf(sq2 * (1.f / 512.f) - mu2 * mu2 + EPSV);
    xb[row * 512 + c]     = f2bf((o0 - mu2) * rstd2 * ln1[c] + ln1[512 + c]);
    xb[row * 512 + c + 1] = f2bf((o1 - mu2) * rstd2 * ln1[c + 1] + ln1[512 + c + 1]);
  } else {
    // ---- gp: per-pixel channel dot + bias -> jdv image part + region pool atomics ----
    int idx = bx - 160;
    int b = idx >> 6, row0 = (idx & 63) * 16;
    int l = t & 63, w = t >> 6;
    bf16x8 wv = *(const bf16x8*)(gpw + l * 8);
    float wf[8];
    #pragma unroll
    for (int j = 0; j < 8; ++j) wf[j] = bf2f((ushort)wv[j]);
    float bias0 = b0[0];
    #pragma unroll
    for (int rr = 0; rr < 4; ++rr) {
      int hw = row0 + w * 4 + rr;
      bf16x8 xv = *(const bf16x8*)(dwT2 + ((size_t)(b * HWP + hw)) * CH + l * 8);
      float s = 0.0f;
      #pragma unroll
      for (int j = 0; j < 8; ++j) s += wf[j] * bf2f((ushort)xv[j]);
      #pragma unroll
      for (int off = 1; off < 64; off <<= 1) s += __shfl_xor(s, off);
      if (l == 0) {
        float sf = s + bias0;
        jdv[b * NTP + NPRM + hw] = sf;
        int y = hw >> 5, xx = hw & 31;
        int rg = (y >> 4) * 4 + (xx >> 3);
        atomicAdd(&jdv[b * NTP + rg], sf * (1.0f / 128.0f));
      }
    }
  }
}

// ---------------- row LayerNorm -> bf16 (ln2) ----------------
__global__ __launch_bounds__(128) void ln_rows_bf(
    const float* __restrict__ in, const float* __restrict__ lnp, ushort* __restrict__ out)
{
  int row = blockIdx.x;
  float4 val = ((const float4*)(in + (size_t)row * CH))[threadIdx.x];
  float sum = val.x + val.y + val.z + val.w;
  float sq = val.x * val.x + val.y * val.y + val.z * val.z + val.w * val.w;
  #pragma unroll
  for (int off = 1; off < 64; off <<= 1) { sum += __shfl_xor(sum, off); sq += __shfl_xor(sq, off); }
  __shared__ float s2[4];
  if ((threadIdx.x & 63) == 0) { s2[(threadIdx.x >> 6) * 2] = sum; s2[(threadIdx.x >> 6) * 2 + 1] = sq; }
  __syncthreads();
  sum = s2[0] + s2[2]; sq = s2[1] + s2[3];
  float mu = sum * (1.0f / 512.0f);
  float var = sq * (1.0f / 512.0f) - mu * mu;
  float rstd = rsqrtf(var + EPSV);
  int c = threadIdx.x * 4;
  ushort4 o;
  o.x = f2bf((val.x - mu) * rstd * lnp[c] + lnp[CH + c]);
  o.y = f2bf((val.y - mu) * rstd * lnp[c + 1] + lnp[CH + c + 1]);
  o.z = f2bf((val.z - mu) * rstd * lnp[c + 2] + lnp[CH + c + 2]);
  o.w = f2bf((val.w - mu) * rstd * lnp[c + 3] + lnp[CH + c + 3]);
  *(ushort4*)(out + (size_t)row * CH + c) = o;
}

// -------- dwt for out_proj: reads token-major jt, dw3x3 + BN + GELU -> bf16 [b*hw][c] --------
__global__ __launch_bounds__(256) void dwt_op(
    const float* __restrict__ jt, const float* __restrict__ w9p,
    const float* __restrict__ bn, ushort* __restrict__ outT)
{
  __shared__ float Tt[3][32][33];
  const int y = blockIdx.x;
  const int c0 = blockIdx.y * 32;
  const int b = blockIdx.z;
  const int tx = threadIdx.x, ty = threadIdx.y;
  #pragma unroll
  for (int ry = 0; ry < 3; ++ry) {
    int yy = y - 1 + ry;
    bool ok = (unsigned)yy < 32u;
    #pragma unroll
    for (int it = 0; it < 4; ++it) {
      int px = ty + it * 8;
      float v = ok ? jt[((size_t)(b * NTOK + NPRM + yy * 32 + px)) * 512 + c0 + tx] : 0.0f;
      Tt[ry][px][tx] = v;
    }
  }
  __syncthreads();
  int c = c0 + tx;
  float w9[9];
  #pragma unroll
  for (int k = 0; k < 9; ++k) w9[k] = w9p[c * 9 + k];
  float g = bn[c], be = bn[CH + c], mm = bn[2 * CH + c], vv = bn[3 * CH + c];
  float s = g * rsqrtf(vv + EPSV);
  float sh = be - mm * s;
  #pragma unroll
  for (int it = 0; it < 4; ++it) {
    int px = ty + it * 8;
    float acc = 0.0f;
    #pragma unroll
    for (int dy = 0; dy < 3; ++dy) {
      #pragma unroll
      for (int dx = 0; dx < 3; ++dx) {
        int xx = px + dx - 1;
        if ((unsigned)xx < 32u) acc += Tt[dy][xx][tx] * w9[dy * 3 + dx];
      }
    }
    outT[((size_t)(b * HWP + y * 32 + px)) * CH + c] = f2bf(gelu_f(acc * s + sh));
  }
}

// ---------------- MFMA flash attention (exp2 domain), 4 waves, LDS-staged K/V ----------------
__device__ __forceinline__ void tok_coord(int idx, float& y, float& x)
{
  if (idx < NPRM) { y = (float)(idx >> 2); x = (float)(idx & 3) * (1.0f / 3.0f); }
  else { int t = idx - NPRM; y = (float)(t >> 5) * (1.0f / 31.0f); x = (float)(t & 31) * (1.0f / 31.0f); }
}

__global__ __launch_bounds__(256) void attn_mfma2(
    const ushort* __restrict__ qh, const ushort* __restrict__ kh,
    const ushort* __restrict__ vT, const float* __restrict__ jd,
    const float* __restrict__ gw, ushort* __restrict__ ao)
{
  __shared__ ushort sK[8192], sV[8192];
  __shared__ ushort Pl[4][16][72];
  const int t = threadIdx.x, l = t & 63, w = t >> 6;
  const int h = blockIdx.y, b = blockIdx.z;
  const int i0 = blockIdx.x * 64 + w * 16;
  const ushort* Q = qh + (size_t)(b * 8 + h) * NTP * 64;
  const ushort* K = kh + (size_t)(b * 8 + h) * NTP * 64;
  const ushort* V = vT + (size_t)(b * 8 + h) * 64 * NTP;
  const float decay = logf(1.0f - exp2f(-1.0f - 0.5f * (float)h)) * LOG2E;
  const float g0 = gw[0] * decay, g1 = gw[1] * decay;

  bf16x8 qf0 = *(const bf16x8*)(Q + (size_t)(i0 + (l & 15)) * 64 + (l >> 4) * 8);
  bf16x8 qf1 = *(const bf16x8*)(Q + (size_t)(i0 + (l & 15)) * 64 + 32 + (l >> 4) * 8);

  float yi[4], xi[4], jdi[4];
  #pragma unroll
  for (int r = 0; r < 4; ++r) {
    int i = i0 + (l >> 4) * 4 + r;
    tok_coord(i, yi[r], xi[r]);
    jdi[r] = jd[b * NTP + i];
  }

  float m_r[4] = { -1e30f, -1e30f, -1e30f, -1e30f };
  float l_r[4] = { 0.f, 0.f, 0.f, 0.f };
  f32x4 of[4];
  { f32x4 z = {0.f, 0.f, 0.f, 0.f};
    #pragma unroll
    for (int d = 0; d < 4; ++d) of[d] = z; }

#define ASTAGE(buf, j0s) { \
    const ushort* gk = K + (size_t)((j0s) + l) * 64; \
    const ushort* gv = V + (size_t)l * NTP + (j0s); \
    gl16(gk + w * 8,       sK + (buf) * 4096 + w * 512); \
    gl16(gk + (w + 4) * 8, sK + (buf) * 4096 + (w + 4) * 512); \
    gl16(gv + w * 8,       sV + (buf) * 4096 + w * 512); \
    gl16(gv + (w + 4) * 8, sV + (buf) * 4096 + (w + 4) * 512); }

  ASTAGE(0, 0)
  __syncthreads();
  const int NJT = 17;
  for (int jti = 0; jti < NJT; ++jti) {
    const int j0 = jti * 64;
    if (jti + 1 < NJT) ASTAGE((jti + 1) & 1, j0 + 64)
    const ushort* bK = sK + (jti & 1) * 4096;
    const ushort* bV = sV + (jti & 1) * 4096;

    f32x4 sfr[4];
    #pragma unroll
    for (int jf = 0; jf < 4; ++jf) {
      bf16x8 k0 = *(const bf16x8*)(bK + (((l >> 4)) * 64 + jf * 16 + (l & 15)) * 8);
      bf16x8 k1 = *(const bf16x8*)(bK + ((4 + (l >> 4)) * 64 + jf * 16 + (l & 15)) * 8);
      f32x4 z = {0.f, 0.f, 0.f, 0.f};
      z = __builtin_amdgcn_mfma_f32_16x16x32_bf16(qf0, k0, z, 0, 0, 0);
      z = __builtin_amdgcn_mfma_f32_16x16x32_bf16(qf1, k1, z, 0, 0, 0);
      sfr[jf] = z;
    }
    float pvv[4][4];
    float mt[4] = { -1e30f, -1e30f, -1e30f, -1e30f };
    #pragma unroll
    for (int jf = 0; jf < 4; ++jf) {
      int jj = j0 + jf * 16 + (l & 15);
      float yj, xj;
      tok_coord(jj, yj, xj);
      float jdj = jd[b * NTP + jj];
      bool valid = jj < NTOK;
      #pragma unroll
      for (int r = 0; r < 4; ++r) {
        float bias = g0 * (fabsf(yi[r] - yj) + fabsf(xi[r] - xj)) + g1 * fabsf(jdi[r] - jdj);
        float sv = valid ? (sfr[jf][r] + bias) : -1e30f;
        pvv[jf][r] = sv;
        mt[r] = fmaxf(mt[r], sv);
      }
    }
    #pragma unroll
    for (int r = 0; r < 4; ++r) {
      #pragma unroll
      for (int off = 1; off < 16; off <<= 1) mt[r] = fmaxf(mt[r], __shfl_xor(mt[r], off));
    }
    float alpha[4], ls[4];
    #pragma unroll
    for (int r = 0; r < 4; ++r) {
      float mn = fmaxf(m_r[r], mt[r]);
      alpha[r] = exp2f(m_r[r] - mn);
      m_r[r] = mn;
      ls[r] = 0.f;
    }
    #pragma unroll
    for (int jf = 0; jf < 4; ++jf) {
      #pragma unroll
      for (int r = 0; r < 4; ++r) {
        float pp = exp2f(pvv[jf][r] - m_r[r]);
        pvv[jf][r] = pp;
        ls[r] += pp;
      }
    }
    #pragma unroll
    for (int r = 0; r < 4; ++r) {
      #pragma unroll
      for (int off = 1; off < 16; off <<= 1) ls[r] += __shfl_xor(ls[r], off);
      l_r[r] = l_r[r] * alpha[r] + ls[r];
    }
    #pragma unroll
    for (int d = 0; d < 4; ++d) {
      #pragma unroll
      for (int r = 0; r < 4; ++r) of[d][r] *= alpha[r];
    }
    #pragma unroll
    for (int jf = 0; jf < 4; ++jf) {
      #pragma unroll
      for (int r = 0; r < 4; ++r)
        Pl[w][(l >> 4) * 4 + r][jf * 16 + (l & 15)] = f2bf(pvv[jf][r]);
    }
    asm volatile("s_waitcnt lgkmcnt(0)" ::: "memory");
    bf16x8 pa0 = *(const bf16x8*)&Pl[w][l & 15][(l >> 4) * 8];
    bf16x8 pa1 = *(const bf16x8*)&Pl[w][l & 15][32 + (l >> 4) * 8];
    #pragma unroll
    for (int df = 0; df < 4; ++df) {
      bf16x8 v0 = *(const bf16x8*)(bV + (((l >> 4)) * 64 + df * 16 + (l & 15)) * 8);
      bf16x8 v1 = *(const bf16x8*)(bV + ((4 + (l >> 4)) * 64 + df * 16 + (l & 15)) * 8);
      of[df] = __builtin_amdgcn_mfma_f32_16x16x32_bf16(pa0, v0, of[df], 0, 0, 0);
      of[df] = __builtin_amdgcn_mfma_f32_16x16x32_bf16(pa1, v1, of[df], 0, 0, 0);
    }
    __syncthreads();
  }
  #pragma unroll
  for (int r = 0; r < 4; ++r) {
    int i = i0 + (l >> 4) * 4 + r;
    if (i < NTOK) {
      float inv = 1.0f / l_r[r];
      #pragma unroll
      for (int df = 0; df < 4; ++df)
        ao[((size_t)(b * NTOK + i)) * 512 + h * 64 + df * 16 + (l & 15)] = f2bf(of[df][r] * inv);
    }
  }
}

// ---------------- host ----------------
extern "C" void kernel_launch(void* const* d_in, const int* in_sizes, int n_in,
                              void* d_out, int out_size, void* d_ws, size_t ws_size,
                              hipStream_t stream)
{
  const float* fused = (const float*)d_in[0];
  const float* depth = (const float*)d_in[1];
  const float* pg_dw_w = (const float*)d_in[2];
  const float* pg_bn1 = (const float*)d_in[3];
  const float* pg_pw_w = (const float*)d_in[4];
  const float* pg_bn2 = (const float*)d_in[5];
  const float* prompt_embed = (const float*)d_in[6];
  const float* pg_ln = (const float*)d_in[7];
  const float* gp_dw_w = (const float*)d_in[8];
  const float* gp_bn = (const float*)d_in[9];
  const float* gp_pw_w = (const float*)d_in[10];
  const float* gp_pw_b = (const float*)d_in[11];
  const float* gp_weight = (const float*)d_in[12];
  const float* ln1 = (const float*)d_in[13];
  const float* wq = (const float*)d_in[14];
  const float* wk = (const float*)d_in[15];
  const float* wv = (const float*)d_in[16];
  const float* wo = (const float*)d_in[17];
  const float* ln2 = (const float*)d_in[18];
  const float* mlp_w1 = (const float*)d_in[19];
  const float* mlp_b1 = (const float*)d_in[20];
  const float* mlp_w2 = (const float*)d_in[21];
  const float* mlp_b2 = (const float*)d_in[22];
  const float* op_dw_w = (const float*)d_in[23];
  const float* op_bn1 = (const float*)d_in[24];
  const float* op_pw_w = (const float*)d_in[25];
  const float* op_bn2 = (const float*)d_in[26];
  float* out = (float*)d_out;

  char* p = (char*)d_ws;
  auto alloc = [&](size_t bytes) { char* r = p; p += (bytes + 1023) & ~(size_t)1023; return r; };
  float*  jdv   = (float*) alloc((size_t)BB * NTP * 4);          // 17408 B
  float*  ppool = (float*) alloc((size_t)BB * 8 * CH * 4);       // 65536 B (contiguous after jdv)
  float*  jt    = (float*) alloc((size_t)MTOK * 512 * 4);
  ushort* xb    = (ushort*)alloc((size_t)MPAD * 512 * 2);
  ushort* hb    = (ushort*)alloc((size_t)MPAD * 1024 * 2);
  ushort* ao    = (ushort*)alloc((size_t)MPAD * 512 * 2);
  ushort* qhB   = (ushort*)alloc((size_t)32 * NTP * 64 * 2);
  ushort* khB   = (ushort*)alloc((size_t)32 * NTP * 64 * 2);
  ushort* vTB   = (ushort*)alloc((size_t)32 * NTP * 64 * 2);
  ushort* dwT1  = (ushort*)alloc((size_t)BB * HWP * CH * 2);
  ushort* dwT2  = (ushort*)alloc((size_t)BB * HWP * CH * 2);
  ushort* wbf   = (ushort*)alloc((size_t)2621952 * 2);

  ushort* wqkv_bf = wbf;
  ushort* wo_bf   = wbf + 786432;
  ushort* w1_bf   = wbf + 1048576;
  ushort* w2_bf   = wbf + 1572864;
  ushort* pgw_bf  = wbf + 2097152;
  ushort* opw_bf  = wbf + 2359296;
  ushort* gpw_bf  = wbf + 2621440;

  // zero the atomic accumulators (jdv + ppool are contiguous)
  hipMemsetAsync(jdv, 0, (size_t)BB * NTP * 4 + 1024 /*pad*/ + (size_t)BB * 8 * CH * 4 - 1024, stream);
  hipMemsetAsync(ppool, 0, (size_t)BB * 8 * CH * 4, stream);

  hipLaunchKernelGGL(convw, dim3(2048), dim3(256), 0, stream,
                     wq, wk, wv, wo, mlp_w1, mlp_w2, pg_pw_w, op_pw_w, gp_pw_w, wbf);

  // depth -> pg & gp dw paths (one pass)
  hipLaunchKernelGGL(dwt_dual, dim3(32, 16, BB), dim3(32, 8), 0, stream,
                     depth, pg_dw_w, pg_bn1, gp_dw_w, gp_bn, dwT1, dwT2);
  // pg pointwise + fused pooling
  hipLaunchKernelGGL(gemm_pw_pool, dim3(8, 4, BB), dim3(256), 0, stream, pgw_bf, dwT1, pg_bn2, ppool);
  // combo: img tokenize+LN1 | prompt pg_ln+LN1 | gp dot + pool
  hipLaunchKernelGGL(combo_mid, dim3(416), dim3(256), 0, stream,
                     fused, ppool, prompt_embed, pg_ln, ln1, jt, xb, dwT2, gpw_bf, gp_pw_b, jdv);
  // mixer
  hipLaunchKernelGGL(gemm_qkv128, dim3(12, 33), dim3(256), 0, stream, xb, wqkv_bf, qhB, khB, vTB);
  hipLaunchKernelGGL(attn_mfma2, dim3(17, 8, BB), dim3(256), 0, stream, qhB, khB, vTB, jdv, gp_weight, ao);
  hipLaunchKernelGGL(gemm_res128, dim3(4, 33), dim3(256), 0, stream, ao, wo_bf, jt, (const float*)nullptr, 512);
  hipLaunchKernelGGL(ln_rows_bf, dim3(MTOK), dim3(128), 0, stream, jt, ln2, xb);
  hipLaunchKernelGGL(gemm_gelu128, dim3(8, 33), dim3(256), 0, stream, xb, w1_bf, mlp_b1, hb);
  hipLaunchKernelGGL(gemm_res128, dim3(4, 33), dim3(256), 0, stream, hb, w2_bf, jt, mlp_b2, 1024);
  // out_proj
  hipLaunchKernelGGL(dwt_op, dim3(32, 16, BB), dim3(32, 8), 0, stream, jt, op_dw_w, op_bn1, dwT1);
  hipLaunchKernelGGL(gemm_pw_res, dim3(8, 4, BB), dim3(256), 0, stream, opw_bf, dwT1, op_bn2, fused, out);
}

// Round 8
// 331.627 us; speedup vs baseline: 1.1769x; 1.1708x over previous
//
#include <hip/hip_runtime.h>
#include <math.h>

typedef __attribute__((ext_vector_type(8))) short bf16x8;
typedef __attribute__((ext_vector_type(4))) float f32x4;

#define CH 512
#define HWP 1024
#define NTOK 1032
#define NTP 1088
#define NPRM 8
#define BB 4
#define EPSV 1e-5f
#define MTOK 4128
#define MPAD 4224
#define QSCL 0.18033688f   // 0.125 * log2(e)
#define LOG2E 1.44269504f

__device__ __forceinline__ float gelu_f(float x) {
  return 0.5f * x * (1.0f + erff(x * 0.70710678118654752440f));
}

__device__ __forceinline__ ushort f2bf(float x) {
  union { float f; unsigned u; } v; v.f = x;
  unsigned r = v.u + 0x7FFF + ((v.u >> 16) & 1);
  return (ushort)(r >> 16);
}

__device__ __forceinline__ float bf2f(ushort u) {
  union { unsigned u; float f; } v; v.u = ((unsigned)u) << 16;
  return v.f;
}

__device__ __forceinline__ void gl16(const ushort* g, ushort* s) {
  __builtin_amdgcn_global_load_lds(
      (const __attribute__((address_space(1))) unsigned int*)g,
      (__attribute__((address_space(3))) unsigned int*)s,
      16, 0, 0);
}

// ---------------- weight fp32 -> bf16 (packed arena) ----------------
__global__ __launch_bounds__(256) void convw(
    const float* __restrict__ wq, const float* __restrict__ wk, const float* __restrict__ wv,
    const float* __restrict__ wo, const float* __restrict__ w1, const float* __restrict__ w2,
    const float* __restrict__ pgw, const float* __restrict__ opw, const float* __restrict__ gpw,
    ushort* __restrict__ out)
{
  const int total = 2621952;
  for (int i = blockIdx.x * 256 + threadIdx.x; i < total; i += gridDim.x * 256) {
    const float* src; int off;
    if (i < 262144)       { src = wq;  off = i; }
    else if (i < 524288)  { src = wk;  off = i - 262144; }
    else if (i < 786432)  { src = wv;  off = i - 524288; }
    else if (i < 1048576) { src = wo;  off = i - 786432; }
    else if (i < 1572864) { src = w1;  off = i - 1048576; }
    else if (i < 2097152) { src = w2;  off = i - 1572864; }
    else if (i < 2359296) { src = pgw; off = i - 2097152; }
    else if (i < 2621440) { src = opw; off = i - 2359296; }
    else                  { src = gpw; off = i - 2621440; }
    out[i] = f2bf(src[off]);
  }
}

// -------- fused DUAL dw3x3 + BN + GELU + transpose -> bf16 [b*hw][c] --------
__global__ __launch_bounds__(256) void dwt_dual(
    const float* __restrict__ in,
    const float* __restrict__ w1p, const float* __restrict__ bn1,
    const float* __restrict__ w2p, const float* __restrict__ bn2,
    ushort* __restrict__ o1, ushort* __restrict__ o2)
{
  __shared__ float t1[32][33];
  __shared__ float t2[32][33];
  const int y = blockIdx.x;
  const int c0 = blockIdx.y * 32;
  const int b = blockIdx.z;
  const int tx = threadIdx.x, ty = threadIdx.y;
  #pragma unroll
  for (int i = 0; i < 4; ++i) {
    int c = c0 + ty + i * 8;
    const float* ip = in + ((size_t)(b * CH + c)) * HWP;
    const float* wa = w1p + c * 9;
    const float* wb = w2p + c * 9;
    float a1 = 0.0f, a2 = 0.0f;
    #pragma unroll
    for (int dy = 0; dy < 3; ++dy) {
      int yy = y + dy - 1;
      if ((unsigned)yy < 32u) {
        #pragma unroll
        for (int dx = 0; dx < 3; ++dx) {
          int xx = tx + dx - 1;
          if ((unsigned)xx < 32u) {
            float v = ip[yy * 32 + xx];
            a1 += v * wa[dy * 3 + dx];
            a2 += v * wb[dy * 3 + dx];
          }
        }
      }
    }
    float g1 = bn1[c], be1 = bn1[CH + c], m1 = bn1[2 * CH + c], v1 = bn1[3 * CH + c];
    float s1 = g1 * rsqrtf(v1 + EPSV);
    t1[ty + i * 8][tx] = gelu_f(a1 * s1 + (be1 - m1 * s1));
    float g2 = bn2[c], be2 = bn2[CH + c], m2 = bn2[2 * CH + c], v2 = bn2[3 * CH + c];
    float s2 = g2 * rsqrtf(v2 + EPSV);
    t2[ty + i * 8][tx] = gelu_f(a2 * s2 + (be2 - m2 * s2));
  }
  __syncthreads();
  #pragma unroll
  for (int i = 0; i < 4; ++i) {
    size_t row = (size_t)(b * HWP + y * 32 + ty + i * 8) * CH + c0 + tx;
    o1[row] = f2bf(t1[tx][ty + i * 8]);
    o2[row] = f2bf(t2[tx][ty + i * 8]);
  }
}

// ============ GEMM core: 64x64 tile, K staged in strips of 256 elems ============
// LDS strip: [64 rows][256 ush] row-major (512B rows), chunk c (16B units) holds
// global chunk c ^ (row&7). One gl16 stages 2 full rows (1KB).
template<int KH>  // number of 256-elem K strips (K = KH*256)
__device__ __forceinline__ void g64_core(
    const ushort* __restrict__ Ab, const ushort* __restrict__ Bb,
    int KA, int KB, ushort* sA, ushort* sB,
    f32x4 (&acc)[2][2], int l, int w)
{
  const int wr = (w >> 1) * 32, wc = (w & 1) * 32;
  #pragma unroll
  for (int kh = 0; kh < KH; ++kh) {
    if (kh) __syncthreads();
    #pragma unroll
    for (int j = 0; j < 8; ++j) {
      int r2 = w * 16 + j * 2;
      int row = r2 + (l >> 5);
      int chk = (l & 31) ^ (row & 7);
      gl16(Ab + (size_t)row * KA + kh * 256 + chk * 8, sA + r2 * 256);
      gl16(Bb + (size_t)row * KB + kh * 256 + chk * 8, sB + r2 * 256);
    }
    __syncthreads();
    #pragma unroll
    for (int kt = 0; kt < 8; ++kt) {
      int q = kt * 4 + (l >> 4);
      int r0 = wr + (l & 15), r1 = wr + 16 + (l & 15);
      int c0i = wc + (l & 15), c1i = wc + 16 + (l & 15);
      bf16x8 a0 = *(const bf16x8*)(sA + r0 * 256 + ((q ^ (r0 & 7)) * 8));
      bf16x8 a1 = *(const bf16x8*)(sA + r1 * 256 + ((q ^ (r1 & 7)) * 8));
      bf16x8 b0 = *(const bf16x8*)(sB + c0i * 256 + ((q ^ (c0i & 7)) * 8));
      bf16x8 b1 = *(const bf16x8*)(sB + c1i * 256 + ((q ^ (c1i & 7)) * 8));
      acc[0][0] = __builtin_amdgcn_mfma_f32_16x16x32_bf16(a0, b0, acc[0][0], 0, 0, 0);
      acc[0][1] = __builtin_amdgcn_mfma_f32_16x16x32_bf16(a0, b1, acc[0][1], 0, 0, 0);
      acc[1][0] = __builtin_amdgcn_mfma_f32_16x16x32_bf16(a1, b0, acc[1][0], 0, 0, 0);
      acc[1][1] = __builtin_amdgcn_mfma_f32_16x16x32_bf16(a1, b1, acc[1][1], 0, 0, 0);
    }
  }
}

#define G64_PRE(Abase, Bbase, KAv, KBv, KHv) \
  __shared__ ushort sA[16384], sB[16384]; \
  f32x4 acc[2][2]; \
  { f32x4 z = {0.f, 0.f, 0.f, 0.f}; acc[0][0] = z; acc[0][1] = z; acc[1][0] = z; acc[1][1] = z; } \
  const int l = threadIdx.x & 63, w = threadIdx.x >> 6; \
  const int wr = (w >> 1) * 32, wc = (w & 1) * 32; \
  g64_core<KHv>((Abase), (Bbase), (KAv), (KBv), sA, sB, acc, l, w);

// QKV fused: A=xb [MPAD][512], B=wqkv [1536][512]
__global__ __launch_bounds__(256) void g_qkv(
    const ushort* __restrict__ A, const ushort* __restrict__ B,
    ushort* __restrict__ qh, ushort* __restrict__ kh, ushort* __restrict__ vt)
{
  const int n0 = blockIdx.x * 64, m0 = blockIdx.y * 64;
  G64_PRE(A + (size_t)m0 * 512, B + (size_t)n0 * 512, 512, 512, 2)
  #pragma unroll
  for (int nf = 0; nf < 2; ++nf) {
    int n = n0 + wc + nf * 16 + (l & 15);
    #pragma unroll
    for (int mf = 0; mf < 2; ++mf) {
      #pragma unroll
      for (int r = 0; r < 4; ++r) {
        int m = m0 + wr + mf * 16 + (l >> 4) * 4 + r;
        if (m < MTOK) {
          int b = m / NTOK;
          int tok = m - b * NTOK;
          float val = acc[mf][nf][r];
          if (n < 512) {
            qh[((size_t)((b * 8 + (n >> 6)) * NTP) + tok) * 64 + (n & 63)] = f2bf(val * QSCL);
          } else if (n < 1024) {
            int n2 = n - 512;
            kh[((size_t)((b * 8 + (n2 >> 6)) * NTP) + tok) * 64 + (n2 & 63)] = f2bf(val);
          } else {
            int n2 = n - 1024;
            vt[((size_t)((b * 8 + (n2 >> 6)) * 64) + (n2 & 63)) * NTP + tok] = f2bf(val);
          }
        }
      }
    }
  }
}

// residual: Cf[m*512+n] += acc + bias
template<int KH>
__global__ __launch_bounds__(256) void g_res(
    const ushort* __restrict__ A, const ushort* __restrict__ B,
    float* __restrict__ Cf, const float* __restrict__ bias)
{
  const int n0 = blockIdx.x * 64, m0 = blockIdx.y * 64;
  G64_PRE(A + (size_t)m0 * (KH * 256), B + (size_t)n0 * (KH * 256), KH * 256, KH * 256, KH)
  #pragma unroll
  for (int nf = 0; nf < 2; ++nf) {
    int n = n0 + wc + nf * 16 + (l & 15);
    float bv = bias ? bias[n] : 0.0f;
    #pragma unroll
    for (int mf = 0; mf < 2; ++mf) {
      #pragma unroll
      for (int r = 0; r < 4; ++r) {
        int m = m0 + wr + mf * 16 + (l >> 4) * 4 + r;
        if (m < MTOK) Cf[(size_t)m * 512 + n] += acc[mf][nf][r] + bv;
      }
    }
  }
}

// mlp1: bias + gelu -> bf16 [m][1024]
__global__ __launch_bounds__(256) void g_gelu(
    const ushort* __restrict__ A, const ushort* __restrict__ B,
    const float* __restrict__ bias, ushort* __restrict__ Ob)
{
  const int n0 = blockIdx.x * 64, m0 = blockIdx.y * 64;
  G64_PRE(A + (size_t)m0 * 512, B + (size_t)n0 * 512, 512, 512, 2)
  #pragma unroll
  for (int nf = 0; nf < 2; ++nf) {
    int n = n0 + wc + nf * 16 + (l & 15);
    float bv = bias[n];
    #pragma unroll
    for (int mf = 0; mf < 2; ++mf) {
      #pragma unroll
      for (int r = 0; r < 4; ++r) {
        int m = m0 + wr + mf * 16 + (l >> 4) * 4 + r;
        if (m < MTOK) Ob[(size_t)m * 1024 + n] = f2bf(gelu_f(acc[mf][nf][r] + bv));
      }
    }
  }
}

// pg pointwise: BN + GELU, pooled only. ppool pre-zeroed.
__global__ __launch_bounds__(256) void g_pw_pool(
    const ushort* __restrict__ A, const ushort* __restrict__ B,
    const float* __restrict__ bnp, float* __restrict__ ppool)
{
  __shared__ float poolL[8][64];
  const int hw0 = blockIdx.x * 64, m0 = blockIdx.y * 64;
  const int b = blockIdx.z;
  {
    int t = threadIdx.x;
    #pragma unroll
    for (int k = 0; k < 2; ++k) { int idx = t + k * 256; poolL[idx >> 6][idx & 63] = 0.0f; }
  }
  G64_PRE(A + (size_t)m0 * 512, B + (size_t)(b * HWP + hw0) * 512, 512, 512, 2)
  __syncthreads();
  #pragma unroll
  for (int mf = 0; mf < 2; ++mf) {
    #pragma unroll
    for (int r = 0; r < 4; ++r) {
      int ol = wr + mf * 16 + (l >> 4) * 4 + r;
      int o = m0 + ol;
      float g = bnp[o], be = bnp[CH + o], mm = bnp[2 * CH + o], vv = bnp[3 * CH + o];
      float s = g * rsqrtf(vv + EPSV);
      float sh = be - mm * s;
      #pragma unroll
      for (int nf = 0; nf < 2; ++nf) {
        int hw = hw0 + wc + nf * 16 + (l & 15);
        float x = gelu_f(acc[mf][nf][r] * s + sh);
        int y = hw >> 5, xx = hw & 31;
        int rg = (y >> 4) * 4 + (xx >> 3);
        atomicAdd(&poolL[rg][ol], x);
      }
    }
  }
  __syncthreads();
  {
    int t = threadIdx.x;
    #pragma unroll
    for (int k = 0; k < 2; ++k) {
      int idx = t + k * 256;
      int rg = idx >> 6, oo = idx & 63;
      float v = poolL[rg][oo];
      if (v != 0.0f)
        atomicAdd(&ppool[((size_t)(b * 8 + rg)) * 512 + m0 + oo], v * (1.0f / 128.0f));
    }
  }
}

// op pointwise: BN + residual add -> out f32 [b][o][hw]
__global__ __launch_bounds__(256) void g_pw_res(
    const ushort* __restrict__ A, const ushort* __restrict__ B,
    const float* __restrict__ bnp, const float* __restrict__ res, float* __restrict__ Of)
{
  const int hw0 = blockIdx.x * 64, m0 = blockIdx.y * 64;
  const int b = blockIdx.z;
  G64_PRE(A + (size_t)m0 * 512, B + (size_t)(b * HWP + hw0) * 512, 512, 512, 2)
  #pragma unroll
  for (int mf = 0; mf < 2; ++mf) {
    #pragma unroll
    for (int r = 0; r < 4; ++r) {
      int o = m0 + wr + mf * 16 + (l >> 4) * 4 + r;
      float g = bnp[o], be = bnp[CH + o], mm = bnp[2 * CH + o], vv = bnp[3 * CH + o];
      float s = g * rsqrtf(vv + EPSV);
      float sh = be - mm * s;
      #pragma unroll
      for (int nf = 0; nf < 2; ++nf) {
        int hw = hw0 + wc + nf * 16 + (l & 15);
        size_t oi = ((size_t)(b * CH + o)) * HWP + hw;
        Of[oi] = acc[mf][nf][r] * s + sh + res[oi];
      }
    }
  }
}

// -------- COMBO: img tokenize+LN1 | prompt pg_ln+LN1 | gp dot + region pool --------
__global__ __launch_bounds__(256) void combo_mid(
    const float* __restrict__ fused, const float* __restrict__ ppool,
    const float* __restrict__ embed, const float* __restrict__ pgln,
    const float* __restrict__ ln1, float* __restrict__ jt, ushort* __restrict__ xb,
    const ushort* __restrict__ dwT2, const ushort* __restrict__ gpw,
    const float* __restrict__ b0, float* __restrict__ jdv)
{
  __shared__ float T[32][513];
  __shared__ float red[16];
  const int t = threadIdx.x;
  const int bx = blockIdx.x;
  if (bx < 128) {
    int b = bx >> 5, hw0 = (bx & 31) * 32;
    int tx = t & 31, ty = t >> 5;
    #pragma unroll
    for (int cc = 0; cc < 512; cc += 8)
      T[tx][cc + ty] = fused[((size_t)(b * 512 + cc + ty)) * 1024 + hw0 + tx];
    __syncthreads();
    int tok = t >> 3, j = t & 7;
    float s = 0.f, sq = 0.f;
    #pragma unroll
    for (int i = 0; i < 64; ++i) {
      float v = T[tok][j * 64 + i];
      s += v; sq += v * v;
    }
    s += __shfl_xor(s, 1); sq += __shfl_xor(sq, 1);
    s += __shfl_xor(s, 2); sq += __shfl_xor(sq, 2);
    s += __shfl_xor(s, 4); sq += __shfl_xor(sq, 4);
    float mu = s * (1.f / 512.f);
    float var = sq * (1.f / 512.f) - mu * mu;
    float rstd = rsqrtf(var + EPSV);
    size_t row = (size_t)(b * NTOK + NPRM + hw0 + tok);
    #pragma unroll
    for (int i = 0; i < 64; i += 4) {
      int c = j * 64 + i;
      float4 v4;
      v4.x = T[tok][c]; v4.y = T[tok][c + 1]; v4.z = T[tok][c + 2]; v4.w = T[tok][c + 3];
      *(float4*)(jt + row * 512 + c) = v4;
      ushort4 u;
      u.x = f2bf((v4.x - mu) * rstd * ln1[c] + ln1[512 + c]);
      u.y = f2bf((v4.y - mu) * rstd * ln1[c + 1] + ln1[512 + c + 1]);
      u.z = f2bf((v4.z - mu) * rstd * ln1[c + 2] + ln1[512 + c + 2]);
      u.w = f2bf((v4.w - mu) * rstd * ln1[c + 3] + ln1[512 + c + 3]);
      *(ushort4*)(xb + row * 512 + c) = u;
    }
  } else if (bx < 160) {
    int idx = bx - 128, b = idx >> 3, pI = idx & 7;
    int c = t * 2;
    float2 v = *(const float2*)(ppool + ((size_t)(b * 8 + pI)) * 512 + c);
    float2 e = *(const float2*)(embed + pI * 512 + c);
    v.x += e.x; v.y += e.y;
    float s = v.x + v.y, sq = v.x * v.x + v.y * v.y;
    #pragma unroll
    for (int off = 1; off < 64; off <<= 1) { s += __shfl_xor(s, off); sq += __shfl_xor(sq, off); }
    if ((t & 63) == 0) { red[(t >> 6) * 2] = s; red[(t >> 6) * 2 + 1] = sq; }
    __syncthreads();
    s = red[0] + red[2] + red[4] + red[6];
    sq = red[1] + red[3] + red[5] + red[7];
    float mu = s * (1.f / 512.f);
    float rstd = rsqrtf(sq * (1.f / 512.f) - mu * mu + EPSV);
    float o0 = (v.x - mu) * rstd * pgln[c] + pgln[512 + c];
    float o1 = (v.y - mu) * rstd * pgln[c + 1] + pgln[512 + c + 1];
    size_t row = (size_t)(b * NTOK + pI);
    jt[row * 512 + c] = o0;
    jt[row * 512 + c + 1] = o1;
    float s2 = o0 + o1, sq2 = o0 * o0 + o1 * o1;
    #pragma unroll
    for (int off = 1; off < 64; off <<= 1) { s2 += __shfl_xor(s2, off); sq2 += __shfl_xor(sq2, off); }
    if ((t & 63) == 0) { red[8 + (t >> 6) * 2] = s2; red[9 + (t >> 6) * 2] = sq2; }
    __syncthreads();
    s2 = red[8] + red[10] + red[12] + red[14];
    sq2 = red[9] + red[11] + red[13] + red[15];
    float mu2 = s2 * (1.f / 512.f);
    float rstd2 = rsqrtf(sq2 * (1.f / 512.f) - mu2 * mu2 + EPSV);
    xb[row * 512 + c]     = f2bf((o0 - mu2) * rstd2 * ln1[c] + ln1[512 + c]);
    xb[row * 512 + c + 1] = f2bf((o1 - mu2) * rstd2 * ln1[c + 1] + ln1[512 + c + 1]);
  } else {
    int idx = bx - 160;
    int b = idx >> 6, row0 = (idx & 63) * 16;
    int l = t & 63, w = t >> 6;
    bf16x8 wv = *(const bf16x8*)(gpw + l * 8);
    float wf[8];
    #pragma unroll
    for (int j = 0; j < 8; ++j) wf[j] = bf2f((ushort)wv[j]);
    float bias0 = b0[0];
    #pragma unroll
    for (int rr = 0; rr < 4; ++rr) {
      int hw = row0 + w * 4 + rr;
      bf16x8 xv = *(const bf16x8*)(dwT2 + ((size_t)(b * HWP + hw)) * CH + l * 8);
      float s = 0.0f;
      #pragma unroll
      for (int j = 0; j < 8; ++j) s += wf[j] * bf2f((ushort)xv[j]);
      #pragma unroll
      for (int off = 1; off < 64; off <<= 1) s += __shfl_xor(s, off);
      if (l == 0) {
        float sf = s + bias0;
        jdv[b * NTP + NPRM + hw] = sf;
        int y = hw >> 5, xx = hw & 31;
        int rg = (y >> 4) * 4 + (xx >> 3);
        atomicAdd(&jdv[b * NTP + rg], sf * (1.0f / 128.0f));
      }
    }
  }
}

// ---------------- row LayerNorm -> bf16 (ln2) ----------------
__global__ __launch_bounds__(128) void ln_rows_bf(
    const float* __restrict__ in, const float* __restrict__ lnp, ushort* __restrict__ out)
{
  int row = blockIdx.x;
  float4 val = ((const float4*)(in + (size_t)row * CH))[threadIdx.x];
  float sum = val.x + val.y + val.z + val.w;
  float sq = val.x * val.x + val.y * val.y + val.z * val.z + val.w * val.w;
  #pragma unroll
  for (int off = 1; off < 64; off <<= 1) { sum += __shfl_xor(sum, off); sq += __shfl_xor(sq, off); }
  __shared__ float s2[4];
  if ((threadIdx.x & 63) == 0) { s2[(threadIdx.x >> 6) * 2] = sum; s2[(threadIdx.x >> 6) * 2 + 1] = sq; }
  __syncthreads();
  sum = s2[0] + s2[2]; sq = s2[1] + s2[3];
  float mu = sum * (1.0f / 512.0f);
  float var = sq * (1.0f / 512.0f) - mu * mu;
  float rstd = rsqrtf(var + EPSV);
  int c = threadIdx.x * 4;
  ushort4 o;
  o.x = f2bf((val.x - mu) * rstd * lnp[c] + lnp[CH + c]);
  o.y = f2bf((val.y - mu) * rstd * lnp[c + 1] + lnp[CH + c + 1]);
  o.z = f2bf((val.z - mu) * rstd * lnp[c + 2] + lnp[CH + c + 2]);
  o.w = f2bf((val.w - mu) * rstd * lnp[c + 3] + lnp[CH + c + 3]);
  *(ushort4*)(out + (size_t)row * CH + c) = o;
}

// -------- dwt for out_proj: reads token-major jt --------
__global__ __launch_bounds__(256) void dwt_op(
    const float* __restrict__ jt, const float* __restrict__ w9p,
    const float* __restrict__ bn, ushort* __restrict__ outT)
{
  __shared__ float Tt[3][32][33];
  const int y = blockIdx.x;
  const int c0 = blockIdx.y * 32;
  const int b = blockIdx.z;
  const int tx = threadIdx.x, ty = threadIdx.y;
  #pragma unroll
  for (int ry = 0; ry < 3; ++ry) {
    int yy = y - 1 + ry;
    bool ok = (unsigned)yy < 32u;
    #pragma unroll
    for (int it = 0; it < 4; ++it) {
      int px = ty + it * 8;
      float v = ok ? jt[((size_t)(b * NTOK + NPRM + yy * 32 + px)) * 512 + c0 + tx] : 0.0f;
      Tt[ry][px][tx] = v;
    }
  }
  __syncthreads();
  int c = c0 + tx;
  float w9[9];
  #pragma unroll
  for (int k = 0; k < 9; ++k) w9[k] = w9p[c * 9 + k];
  float g = bn[c], be = bn[CH + c], mm = bn[2 * CH + c], vv = bn[3 * CH + c];
  float s = g * rsqrtf(vv + EPSV);
  float sh = be - mm * s;
  #pragma unroll
  for (int it = 0; it < 4; ++it) {
    int px = ty + it * 8;
    float acc = 0.0f;
    #pragma unroll
    for (int dy = 0; dy < 3; ++dy) {
      #pragma unroll
      for (int dx = 0; dx < 3; ++dx) {
        int xx = px + dx - 1;
        if ((unsigned)xx < 32u) acc += Tt[dy][xx][tx] * w9[dy * 3 + dx];
      }
    }
    outT[((size_t)(b * HWP + y * 32 + px)) * CH + c] = f2bf(gelu_f(acc * s + sh));
  }
}

// ---------------- MFMA flash attention: FIXED-MAX exp2 softmax, MFMA row-sums ----------------
__device__ __forceinline__ void tok_coord(int idx, float& y, float& x)
{
  if (idx < NPRM) { y = (float)(idx >> 2); x = (float)(idx & 3) * (1.0f / 3.0f); }
  else { int t = idx - NPRM; y = (float)(t >> 5) * (1.0f / 31.0f); x = (float)(t & 31) * (1.0f / 31.0f); }
}

__global__ __launch_bounds__(256) void attn_mfma3(
    const ushort* __restrict__ qh, const ushort* __restrict__ kh,
    const ushort* __restrict__ vT, const float* __restrict__ jd,
    const float* __restrict__ gw, ushort* __restrict__ ao)
{
  __shared__ ushort sK[8192], sV[8192];
  __shared__ ushort Pl[4][16][72];
  __shared__ float jdL[NTP];
  const int t = threadIdx.x, l = t & 63, w = t >> 6;
  const int h = blockIdx.y, b = blockIdx.z;
  const int i0 = blockIdx.x * 64 + w * 16;
  const ushort* Q = qh + (size_t)(b * 8 + h) * NTP * 64;
  const ushort* K = kh + (size_t)(b * 8 + h) * NTP * 64;
  const ushort* V = vT + (size_t)(b * 8 + h) * 64 * NTP;
  const float decay = logf(1.0f - exp2f(-1.0f - 0.5f * (float)h)) * LOG2E;
  const float g0 = gw[0] * decay, g1 = gw[1] * decay;

  for (int i = t; i < NTP; i += 256) jdL[i] = jd[b * NTP + i];

  bf16x8 qf0 = *(const bf16x8*)(Q + (size_t)(i0 + (l & 15)) * 64 + (l >> 4) * 8);
  bf16x8 qf1 = *(const bf16x8*)(Q + (size_t)(i0 + (l & 15)) * 64 + 32 + (l >> 4) * 8);

  // ones B-fragment: column n=0 all ones
  bf16x8 ones;
  {
    short ov = (short)((l & 15) == 0 ? 0x3F80 : 0);
    #pragma unroll
    for (int j = 0; j < 8; ++j) ones[j] = ov;
  }

  f32x4 of[4], lacc;
  { f32x4 z = {0.f, 0.f, 0.f, 0.f};
    #pragma unroll
    for (int d = 0; d < 4; ++d) of[d] = z;
    lacc = z; }

#define ASTAGE(buf, j0s) { \
    const ushort* gk = K + (size_t)((j0s) + l) * 64; \
    const ushort* gv = V + (size_t)l * NTP + (j0s); \
    gl16(gk + w * 8,       sK + (buf) * 4096 + w * 512); \
    gl16(gk + (w + 4) * 8, sK + (buf) * 4096 + (w + 4) * 512); \
    gl16(gv + w * 8,       sV + (buf) * 4096 + w * 512); \
    gl16(gv + (w + 4) * 8, sV + (buf) * 4096 + (w + 4) * 512); }

  ASTAGE(0, 0)
  __syncthreads();

  float yi[4], xi[4], jdi[4];
  #pragma unroll
  for (int r = 0; r < 4; ++r) {
    int i = i0 + (l >> 4) * 4 + r;
    tok_coord(i, yi[r], xi[r]);
    jdi[r] = jdL[i];
  }

  const int NJT = 17;
  for (int jti = 0; jti < NJT; ++jti) {
    const int j0 = jti * 64;
    if (jti + 1 < NJT) ASTAGE((jti + 1) & 1, j0 + 64)
    const ushort* bK = sK + (jti & 1) * 4096;
    const ushort* bV = sV + (jti & 1) * 4096;

    f32x4 sfr[4];
    __builtin_amdgcn_s_setprio(1);
    #pragma unroll
    for (int jf = 0; jf < 4; ++jf) {
      bf16x8 k0 = *(const bf16x8*)(bK + (((l >> 4)) * 64 + jf * 16 + (l & 15)) * 8);
      bf16x8 k1 = *(const bf16x8*)(bK + ((4 + (l >> 4)) * 64 + jf * 16 + (l & 15)) * 8);
      f32x4 z = {0.f, 0.f, 0.f, 0.f};
      z = __builtin_amdgcn_mfma_f32_16x16x32_bf16(qf0, k0, z, 0, 0, 0);
      z = __builtin_amdgcn_mfma_f32_16x16x32_bf16(qf1, k1, z, 0, 0, 0);
      sfr[jf] = z;
    }
    __builtin_amdgcn_s_setprio(0);
    // fixed-max softmax: p = 2^(sv - 4); scale cancels in the final divide
    #pragma unroll
    for (int jf = 0; jf < 4; ++jf) {
      int jj = j0 + jf * 16 + (l & 15);
      float yj, xj;
      tok_coord(jj, yj, xj);
      float jdj = jdL[jj];
      bool valid = jj < NTOK;
      #pragma unroll
      for (int r = 0; r < 4; ++r) {
        float bias = g0 * (fabsf(yi[r] - yj) + fabsf(xi[r] - xj)) + g1 * fabsf(jdi[r] - jdj);
        float p = valid ? exp2f(sfr[jf][r] + bias - 4.0f) : 0.0f;
        Pl[w][(l >> 4) * 4 + r][jf * 16 + (l & 15)] = f2bf(p);
      }
    }
    asm volatile("s_waitcnt lgkmcnt(0)" ::: "memory");
    bf16x8 pa0 = *(const bf16x8*)&Pl[w][l & 15][(l >> 4) * 8];
    bf16x8 pa1 = *(const bf16x8*)&Pl[w][l & 15][32 + (l >> 4) * 8];
    __builtin_amdgcn_s_setprio(1);
    #pragma unroll
    for (int df = 0; df < 4; ++df) {
      bf16x8 v0 = *(const bf16x8*)(bV + (((l >> 4)) * 64 + df * 16 + (l & 15)) * 8);
      bf16x8 v1 = *(const bf16x8*)(bV + ((4 + (l >> 4)) * 64 + df * 16 + (l & 15)) * 8);
      of[df] = __builtin_amdgcn_mfma_f32_16x16x32_bf16(pa0, v0, of[df], 0, 0, 0);
      of[df] = __builtin_amdgcn_mfma_f32_16x16x32_bf16(pa1, v1, of[df], 0, 0, 0);
    }
    lacc = __builtin_amdgcn_mfma_f32_16x16x32_bf16(pa0, ones, lacc, 0, 0, 0);
    lacc = __builtin_amdgcn_mfma_f32_16x16x32_bf16(pa1, ones, lacc, 0, 0, 0);
    __builtin_amdgcn_s_setprio(0);
    __syncthreads();
  }
  #pragma unroll
  for (int r = 0; r < 4; ++r) {
    int i = i0 + (l >> 4) * 4 + r;
    float lsum = __shfl(lacc[r], (l & 48), 64);   // broadcast col 0 of this row group
    if (i < NTOK) {
      float inv = 1.0f / lsum;
      #pragma unroll
      for (int df = 0; df < 4; ++df)
        ao[((size_t)(b * NTOK + i)) * 512 + h * 64 + df * 16 + (l & 15)] = f2bf(of[df][r] * inv);
    }
  }
}

// ---------------- host ----------------
extern "C" void kernel_launch(void* const* d_in, const int* in_sizes, int n_in,
                              void* d_out, int out_size, void* d_ws, size_t ws_size,
                              hipStream_t stream)
{
  const float* fused = (const float*)d_in[0];
  const float* depth = (const float*)d_in[1];
  const float* pg_dw_w = (const float*)d_in[2];
  const float* pg_bn1 = (const float*)d_in[3];
  const float* pg_pw_w = (const float*)d_in[4];
  const float* pg_bn2 = (const float*)d_in[5];
  const float* prompt_embed = (const float*)d_in[6];
  const float* pg_ln = (const float*)d_in[7];
  const float* gp_dw_w = (const float*)d_in[8];
  const float* gp_bn = (const float*)d_in[9];
  const float* gp_pw_w = (const float*)d_in[10];
  const float* gp_pw_b = (const float*)d_in[11];
  const float* gp_weight = (const float*)d_in[12];
  const float* ln1 = (const float*)d_in[13];
  const float* wq = (const float*)d_in[14];
  const float* wk = (const float*)d_in[15];
  const float* wv = (const float*)d_in[16];
  const float* wo = (const float*)d_in[17];
  const float* ln2 = (const float*)d_in[18];
  const float* mlp_w1 = (const float*)d_in[19];
  const float* mlp_b1 = (const float*)d_in[20];
  const float* mlp_w2 = (const float*)d_in[21];
  const float* mlp_b2 = (const float*)d_in[22];
  const float* op_dw_w = (const float*)d_in[23];
  const float* op_bn1 = (const float*)d_in[24];
  const float* op_pw_w = (const float*)d_in[25];
  const float* op_bn2 = (const float*)d_in[26];
  float* out = (float*)d_out;

  char* p = (char*)d_ws;
  auto alloc = [&](size_t bytes) { char* r = p; p += (bytes + 1023) & ~(size_t)1023; return r; };
  float*  jdv   = (float*) alloc((size_t)BB * NTP * 4);
  float*  ppool = (float*) alloc((size_t)BB * 8 * CH * 4);
  float*  jt    = (float*) alloc((size_t)MTOK * 512 * 4);
  ushort* xb    = (ushort*)alloc((size_t)MPAD * 512 * 2);
  ushort* hb    = (ushort*)alloc((size_t)MPAD * 1024 * 2);
  ushort* ao    = (ushort*)alloc((size_t)MPAD * 512 * 2);
  ushort* qhB   = (ushort*)alloc((size_t)32 * NTP * 64 * 2);
  ushort* khB   = (ushort*)alloc((size_t)32 * NTP * 64 * 2);
  ushort* vTB   = (ushort*)alloc((size_t)32 * NTP * 64 * 2);
  ushort* dwT1  = (ushort*)alloc((size_t)BB * HWP * CH * 2);
  ushort* dwT2  = (ushort*)alloc((size_t)BB * HWP * CH * 2);
  ushort* wbf   = (ushort*)alloc((size_t)2621952 * 2);

  ushort* wqkv_bf = wbf;
  ushort* wo_bf   = wbf + 786432;
  ushort* w1_bf   = wbf + 1048576;
  ushort* w2_bf   = wbf + 1572864;
  ushort* pgw_bf  = wbf + 2097152;
  ushort* opw_bf  = wbf + 2359296;
  ushort* gpw_bf  = wbf + 2621440;

  hipMemsetAsync(jdv, 0, (size_t)BB * NTP * 4, stream);
  hipMemsetAsync(ppool, 0, (size_t)BB * 8 * CH * 4, stream);

  hipLaunchKernelGGL(convw, dim3(2048), dim3(256), 0, stream,
                     wq, wk, wv, wo, mlp_w1, mlp_w2, pg_pw_w, op_pw_w, gp_pw_w, wbf);

  hipLaunchKernelGGL(dwt_dual, dim3(32, 16, BB), dim3(32, 8), 0, stream,
                     depth, pg_dw_w, pg_bn1, gp_dw_w, gp_bn, dwT1, dwT2);
  hipLaunchKernelGGL(g_pw_pool, dim3(16, 8, BB), dim3(256), 0, stream, pgw_bf, dwT1, pg_bn2, ppool);
  hipLaunchKernelGGL(combo_mid, dim3(416), dim3(256), 0, stream,
                     fused, ppool, prompt_embed, pg_ln, ln1, jt, xb, dwT2, gpw_bf, gp_pw_b, jdv);
  hipLaunchKernelGGL(g_qkv, dim3(24, 65), dim3(256), 0, stream, xb, wqkv_bf, qhB, khB, vTB);
  hipLaunchKernelGGL(attn_mfma3, dim3(17, 8, BB), dim3(256), 0, stream, qhB, khB, vTB, jdv, gp_weight, ao);
  hipLaunchKernelGGL(g_res<2>, dim3(8, 65), dim3(256), 0, stream, ao, wo_bf, jt, (const float*)nullptr);
  hipLaunchKernelGGL(ln_rows_bf, dim3(MTOK), dim3(128), 0, stream, jt, ln2, xb);
  hipLaunchKernelGGL(g_gelu, dim3(16, 65), dim3(256), 0, stream, xb, w1_bf, mlp_b1, hb);
  hipLaunchKernelGGL(g_res<4>, dim3(8, 65), dim3(256), 0, stream, hb, w2_bf, jt, mlp_b2);
  hipLaunchKernelGGL(dwt_op, dim3(32, 16, BB), dim3(32, 8), 0, stream, jt, op_dw_w, op_bn1, dwT1);
  hipLaunchKernelGGL(g_pw_res, dim3(16, 8, BB), dim3(256), 0, stream, opw_bf, dwT1, op_bn2, fused, out);
}

// Round 9
// 331.564 us; speedup vs baseline: 1.1772x; 1.0002x over previous
//
#include <hip/hip_runtime.h>
#include <math.h>

typedef __attribute__((ext_vector_type(8))) short bf16x8;
typedef __attribute__((ext_vector_type(4))) float f32x4;

#define CH 512
#define HWP 1024
#define NTOK 1032
#define NTP 1152
#define NPRM 8
#define BB 4
#define EPSV 1e-5f
#define MTOK 4128
#define MPAD 4224
#define QSCL 0.18033688f   // 0.125 * log2(e)
#define LOG2E 1.44269504f

__device__ __forceinline__ float gelu_f(float x) {
  return 0.5f * x * (1.0f + erff(x * 0.70710678118654752440f));
}

__device__ __forceinline__ ushort f2bf(float x) {
  union { float f; unsigned u; } v; v.f = x;
  unsigned r = v.u + 0x7FFF + ((v.u >> 16) & 1);
  return (ushort)(r >> 16);
}

__device__ __forceinline__ float bf2f(ushort u) {
  union { unsigned u; float f; } v; v.u = ((unsigned)u) << 16;
  return v.f;
}

__device__ __forceinline__ void gl16(const ushort* g, ushort* s) {
  __builtin_amdgcn_global_load_lds(
      (const __attribute__((address_space(1))) unsigned int*)g,
      (__attribute__((address_space(3))) unsigned int*)s,
      16, 0, 0);
}

// ---------------- weight fp32 -> bf16 (packed arena) ----------------
__global__ __launch_bounds__(256) void convw(
    const float* __restrict__ wq, const float* __restrict__ wk, const float* __restrict__ wv,
    const float* __restrict__ wo, const float* __restrict__ w1, const float* __restrict__ w2,
    const float* __restrict__ pgw, const float* __restrict__ opw, const float* __restrict__ gpw,
    ushort* __restrict__ out)
{
  const int total = 2621952;
  for (int i = blockIdx.x * 256 + threadIdx.x; i < total; i += gridDim.x * 256) {
    const float* src; int off;
    if (i < 262144)       { src = wq;  off = i; }
    else if (i < 524288)  { src = wk;  off = i - 262144; }
    else if (i < 786432)  { src = wv;  off = i - 524288; }
    else if (i < 1048576) { src = wo;  off = i - 786432; }
    else if (i < 1572864) { src = w1;  off = i - 1048576; }
    else if (i < 2097152) { src = w2;  off = i - 1572864; }
    else if (i < 2359296) { src = pgw; off = i - 2097152; }
    else if (i < 2621440) { src = opw; off = i - 2359296; }
    else                  { src = gpw; off = i - 2621440; }
    out[i] = f2bf(src[off]);
  }
}

// -------- fused DUAL dw3x3 + BN + GELU + transpose -> bf16 [b*hw][c] --------
__global__ __launch_bounds__(256) void dwt_dual(
    const float* __restrict__ in,
    const float* __restrict__ w1p, const float* __restrict__ bn1,
    const float* __restrict__ w2p, const float* __restrict__ bn2,
    ushort* __restrict__ o1, ushort* __restrict__ o2)
{
  __shared__ float t1[32][33];
  __shared__ float t2[32][33];
  const int y = blockIdx.x;
  const int c0 = blockIdx.y * 32;
  const int b = blockIdx.z;
  const int tx = threadIdx.x, ty = threadIdx.y;
  #pragma unroll
  for (int i = 0; i < 4; ++i) {
    int c = c0 + ty + i * 8;
    const float* ip = in + ((size_t)(b * CH + c)) * HWP;
    const float* wa = w1p + c * 9;
    const float* wb = w2p + c * 9;
    float a1 = 0.0f, a2 = 0.0f;
    #pragma unroll
    for (int dy = 0; dy < 3; ++dy) {
      int yy = y + dy - 1;
      if ((unsigned)yy < 32u) {
        #pragma unroll
        for (int dx = 0; dx < 3; ++dx) {
          int xx = tx + dx - 1;
          if ((unsigned)xx < 32u) {
            float v = ip[yy * 32 + xx];
            a1 += v * wa[dy * 3 + dx];
            a2 += v * wb[dy * 3 + dx];
          }
        }
      }
    }
    float g1 = bn1[c], be1 = bn1[CH + c], m1 = bn1[2 * CH + c], v1 = bn1[3 * CH + c];
    float s1 = g1 * rsqrtf(v1 + EPSV);
    t1[ty + i * 8][tx] = gelu_f(a1 * s1 + (be1 - m1 * s1));
    float g2 = bn2[c], be2 = bn2[CH + c], m2 = bn2[2 * CH + c], v2 = bn2[3 * CH + c];
    float s2 = g2 * rsqrtf(v2 + EPSV);
    t2[ty + i * 8][tx] = gelu_f(a2 * s2 + (be2 - m2 * s2));
  }
  __syncthreads();
  #pragma unroll
  for (int i = 0; i < 4; ++i) {
    size_t row = (size_t)(b * HWP + y * 32 + ty + i * 8) * CH + c0 + tx;
    o1[row] = f2bf(t1[tx][ty + i * 8]);
    o2[row] = f2bf(t2[tx][ty + i * 8]);
  }
}

// ============ GEMM core: 64x64 tile, K staged in strips of 256 elems ============
template<int KH>
__device__ __forceinline__ void g64_core(
    const ushort* __restrict__ Ab, const ushort* __restrict__ Bb,
    int KA, int KB, ushort* sA, ushort* sB,
    f32x4 (&acc)[2][2], int l, int w)
{
  const int wr = (w >> 1) * 32, wc = (w & 1) * 32;
  #pragma unroll
  for (int kh = 0; kh < KH; ++kh) {
    if (kh) __syncthreads();
    #pragma unroll
    for (int j = 0; j < 8; ++j) {
      int r2 = w * 16 + j * 2;
      int row = r2 + (l >> 5);
      int chk = (l & 31) ^ (row & 7);
      gl16(Ab + (size_t)row * KA + kh * 256 + chk * 8, sA + r2 * 256);
      gl16(Bb + (size_t)row * KB + kh * 256 + chk * 8, sB + r2 * 256);
    }
    __syncthreads();
    #pragma unroll
    for (int kt = 0; kt < 8; ++kt) {
      int q = kt * 4 + (l >> 4);
      int r0 = wr + (l & 15), r1 = wr + 16 + (l & 15);
      int c0i = wc + (l & 15), c1i = wc + 16 + (l & 15);
      bf16x8 a0 = *(const bf16x8*)(sA + r0 * 256 + ((q ^ (r0 & 7)) * 8));
      bf16x8 a1 = *(const bf16x8*)(sA + r1 * 256 + ((q ^ (r1 & 7)) * 8));
      bf16x8 b0 = *(const bf16x8*)(sB + c0i * 256 + ((q ^ (c0i & 7)) * 8));
      bf16x8 b1 = *(const bf16x8*)(sB + c1i * 256 + ((q ^ (c1i & 7)) * 8));
      acc[0][0] = __builtin_amdgcn_mfma_f32_16x16x32_bf16(a0, b0, acc[0][0], 0, 0, 0);
      acc[0][1] = __builtin_amdgcn_mfma_f32_16x16x32_bf16(a0, b1, acc[0][1], 0, 0, 0);
      acc[1][0] = __builtin_amdgcn_mfma_f32_16x16x32_bf16(a1, b0, acc[1][0], 0, 0, 0);
      acc[1][1] = __builtin_amdgcn_mfma_f32_16x16x32_bf16(a1, b1, acc[1][1], 0, 0, 0);
    }
  }
}

#define G64_PRE(Abase, Bbase, KAv, KBv, KHv) \
  __shared__ ushort sA[16384], sB[16384]; \
  f32x4 acc[2][2]; \
  { f32x4 z = {0.f, 0.f, 0.f, 0.f}; acc[0][0] = z; acc[0][1] = z; acc[1][0] = z; acc[1][1] = z; } \
  const int l = threadIdx.x & 63, w = threadIdx.x >> 6; \
  const int wr = (w >> 1) * 32, wc = (w & 1) * 32; \
  g64_core<KHv>((Abase), (Bbase), (KAv), (KBv), sA, sB, acc, l, w);

// QKV fused: A=xb [MPAD][512], B=wqkv [1536][512]; q/k/v ALL coalesced row-major [bh][tok][64]
__global__ __launch_bounds__(256) void g_qkv(
    const ushort* __restrict__ A, const ushort* __restrict__ B,
    ushort* __restrict__ qh, ushort* __restrict__ kh, ushort* __restrict__ vh)
{
  const int n0 = blockIdx.x * 64, m0 = blockIdx.y * 64;
  G64_PRE(A + (size_t)m0 * 512, B + (size_t)n0 * 512, 512, 512, 2)
  #pragma unroll
  for (int nf = 0; nf < 2; ++nf) {
    int n = n0 + wc + nf * 16 + (l & 15);
    ushort* dst = (n < 512) ? qh : (n < 1024 ? kh : vh);
    int n2 = n & 511;
    float scl = (n < 512) ? QSCL : 1.0f;
    #pragma unroll
    for (int mf = 0; mf < 2; ++mf) {
      #pragma unroll
      for (int r = 0; r < 4; ++r) {
        int m = m0 + wr + mf * 16 + (l >> 4) * 4 + r;
        if (m < MTOK) {
          int b = m / NTOK;
          int tok = m - b * NTOK;
          dst[((size_t)((b * 8 + (n2 >> 6)) * NTP) + tok) * 64 + (n2 & 63)] = f2bf(acc[mf][nf][r] * scl);
        }
      }
    }
  }
}

// V transpose: [bh][tok(NTP)][64] -> [bh][64][tok(NTP)]
__global__ __launch_bounds__(256) void transp_v(const ushort* __restrict__ vh, ushort* __restrict__ vT)
{
  __shared__ ushort tile[32][33];
  int tok0 = blockIdx.x * 32, d0 = blockIdx.y * 32;
  int bh = blockIdx.z;
  int tx = threadIdx.x, ty = threadIdx.y;
  #pragma unroll
  for (int i = 0; i < 4; ++i)
    tile[ty + i * 8][tx] = vh[((size_t)bh * NTP + tok0 + ty + i * 8) * 64 + d0 + tx];
  __syncthreads();
  #pragma unroll
  for (int i = 0; i < 4; ++i)
    vT[((size_t)bh * 64 + d0 + ty + i * 8) * NTP + tok0 + tx] = tile[tx][ty + i * 8];
}

// residual: Cf[m*512+n] += acc + bias
template<int KH>
__global__ __launch_bounds__(256) void g_res(
    const ushort* __restrict__ A, const ushort* __restrict__ B,
    float* __restrict__ Cf, const float* __restrict__ bias)
{
  const int n0 = blockIdx.x * 64, m0 = blockIdx.y * 64;
  G64_PRE(A + (size_t)m0 * (KH * 256), B + (size_t)n0 * (KH * 256), KH * 256, KH * 256, KH)
  #pragma unroll
  for (int nf = 0; nf < 2; ++nf) {
    int n = n0 + wc + nf * 16 + (l & 15);
    float bv = bias ? bias[n] : 0.0f;
    #pragma unroll
    for (int mf = 0; mf < 2; ++mf) {
      #pragma unroll
      for (int r = 0; r < 4; ++r) {
        int m = m0 + wr + mf * 16 + (l >> 4) * 4 + r;
        if (m < MTOK) Cf[(size_t)m * 512 + n] += acc[mf][nf][r] + bv;
      }
    }
  }
}

// mlp1: bias + gelu -> bf16 [m][1024]
__global__ __launch_bounds__(256) void g_gelu(
    const ushort* __restrict__ A, const ushort* __restrict__ B,
    const float* __restrict__ bias, ushort* __restrict__ Ob)
{
  const int n0 = blockIdx.x * 64, m0 = blockIdx.y * 64;
  G64_PRE(A + (size_t)m0 * 512, B + (size_t)n0 * 512, 512, 512, 2)
  #pragma unroll
  for (int nf = 0; nf < 2; ++nf) {
    int n = n0 + wc + nf * 16 + (l & 15);
    float bv = bias[n];
    #pragma unroll
    for (int mf = 0; mf < 2; ++mf) {
      #pragma unroll
      for (int r = 0; r < 4; ++r) {
        int m = m0 + wr + mf * 16 + (l >> 4) * 4 + r;
        if (m < MTOK) Ob[(size_t)m * 1024 + n] = f2bf(gelu_f(acc[mf][nf][r] + bv));
      }
    }
  }
}

// pg pointwise: BN + GELU, pooled only. ppool pre-zeroed.
__global__ __launch_bounds__(256) void g_pw_pool(
    const ushort* __restrict__ A, const ushort* __restrict__ B,
    const float* __restrict__ bnp, float* __restrict__ ppool)
{
  __shared__ float poolL[8][64];
  const int hw0 = blockIdx.x * 64, m0 = blockIdx.y * 64;
  const int b = blockIdx.z;
  {
    int t = threadIdx.x;
    #pragma unroll
    for (int k = 0; k < 2; ++k) { int idx = t + k * 256; poolL[idx >> 6][idx & 63] = 0.0f; }
  }
  G64_PRE(A + (size_t)m0 * 512, B + (size_t)(b * HWP + hw0) * 512, 512, 512, 2)
  __syncthreads();
  #pragma unroll
  for (int mf = 0; mf < 2; ++mf) {
    #pragma unroll
    for (int r = 0; r < 4; ++r) {
      int ol = wr + mf * 16 + (l >> 4) * 4 + r;
      int o = m0 + ol;
      float g = bnp[o], be = bnp[CH + o], mm = bnp[2 * CH + o], vv = bnp[3 * CH + o];
      float s = g * rsqrtf(vv + EPSV);
      float sh = be - mm * s;
      #pragma unroll
      for (int nf = 0; nf < 2; ++nf) {
        int hw = hw0 + wc + nf * 16 + (l & 15);
        float x = gelu_f(acc[mf][nf][r] * s + sh);
        int y = hw >> 5, xx = hw & 31;
        int rg = (y >> 4) * 4 + (xx >> 3);
        atomicAdd(&poolL[rg][ol], x);
      }
    }
  }
  __syncthreads();
  {
    int t = threadIdx.x;
    #pragma unroll
    for (int k = 0; k < 2; ++k) {
      int idx = t + k * 256;
      int rg = idx >> 6, oo = idx & 63;
      float v = poolL[rg][oo];
      if (v != 0.0f)
        atomicAdd(&ppool[((size_t)(b * 8 + rg)) * 512 + m0 + oo], v * (1.0f / 128.0f));
    }
  }
}

// op pointwise: BN + residual add -> out f32 [b][o][hw]
__global__ __launch_bounds__(256) void g_pw_res(
    const ushort* __restrict__ A, const ushort* __restrict__ B,
    const float* __restrict__ bnp, const float* __restrict__ res, float* __restrict__ Of)
{
  const int hw0 = blockIdx.x * 64, m0 = blockIdx.y * 64;
  const int b = blockIdx.z;
  G64_PRE(A + (size_t)m0 * 512, B + (size_t)(b * HWP + hw0) * 512, 512, 512, 2)
  #pragma unroll
  for (int mf = 0; mf < 2; ++mf) {
    #pragma unroll
    for (int r = 0; r < 4; ++r) {
      int o = m0 + wr + mf * 16 + (l >> 4) * 4 + r;
      float g = bnp[o], be = bnp[CH + o], mm = bnp[2 * CH + o], vv = bnp[3 * CH + o];
      float s = g * rsqrtf(vv + EPSV);
      float sh = be - mm * s;
      #pragma unroll
      for (int nf = 0; nf < 2; ++nf) {
        int hw = hw0 + wc + nf * 16 + (l & 15);
        size_t oi = ((size_t)(b * CH + o)) * HWP + hw;
        Of[oi] = acc[mf][nf][r] * s + sh + res[oi];
      }
    }
  }
}

// -------- COMBO: img tokenize+LN1 | prompt pg_ln+LN1 | gp dot + region pool --------
__global__ __launch_bounds__(256) void combo_mid(
    const float* __restrict__ fused, const float* __restrict__ ppool,
    const float* __restrict__ embed, const float* __restrict__ pgln,
    const float* __restrict__ ln1, float* __restrict__ jt, ushort* __restrict__ xb,
    const ushort* __restrict__ dwT2, const ushort* __restrict__ gpw,
    const float* __restrict__ b0, float* __restrict__ jdv)
{
  __shared__ float T[32][513];
  __shared__ float red[16];
  const int t = threadIdx.x;
  const int bx = blockIdx.x;
  if (bx < 128) {
    int b = bx >> 5, hw0 = (bx & 31) * 32;
    int tx = t & 31, ty = t >> 5;
    #pragma unroll
    for (int cc = 0; cc < 512; cc += 8)
      T[tx][cc + ty] = fused[((size_t)(b * 512 + cc + ty)) * 1024 + hw0 + tx];
    __syncthreads();
    int tok = t >> 3, j = t & 7;
    float s = 0.f, sq = 0.f;
    #pragma unroll
    for (int i = 0; i < 64; ++i) {
      float v = T[tok][j * 64 + i];
      s += v; sq += v * v;
    }
    s += __shfl_xor(s, 1); sq += __shfl_xor(sq, 1);
    s += __shfl_xor(s, 2); sq += __shfl_xor(sq, 2);
    s += __shfl_xor(s, 4); sq += __shfl_xor(sq, 4);
    float mu = s * (1.f / 512.f);
    float var = sq * (1.f / 512.f) - mu * mu;
    float rstd = rsqrtf(var + EPSV);
    size_t row = (size_t)(b * NTOK + NPRM + hw0 + tok);
    #pragma unroll
    for (int i = 0; i < 64; i += 4) {
      int c = j * 64 + i;
      float4 v4;
      v4.x = T[tok][c]; v4.y = T[tok][c + 1]; v4.z = T[tok][c + 2]; v4.w = T[tok][c + 3];
      *(float4*)(jt + row * 512 + c) = v4;
      ushort4 u;
      u.x = f2bf((v4.x - mu) * rstd * ln1[c] + ln1[512 + c]);
      u.y = f2bf((v4.y - mu) * rstd * ln1[c + 1] + ln1[512 + c + 1]);
      u.z = f2bf((v4.z - mu) * rstd * ln1[c + 2] + ln1[512 + c + 2]);
      u.w = f2bf((v4.w - mu) * rstd * ln1[c + 3] + ln1[512 + c + 3]);
      *(ushort4*)(xb + row * 512 + c) = u;
    }
  } else if (bx < 160) {
    int idx = bx - 128, b = idx >> 3, pI = idx & 7;
    int c = t * 2;
    float2 v = *(const float2*)(ppool + ((size_t)(b * 8 + pI)) * 512 + c);
    float2 e = *(const float2*)(embed + pI * 512 + c);
    v.x += e.x; v.y += e.y;
    float s = v.x + v.y, sq = v.x * v.x + v.y * v.y;
    #pragma unroll
    for (int off = 1; off < 64; off <<= 1) { s += __shfl_xor(s, off); sq += __shfl_xor(sq, off); }
    if ((t & 63) == 0) { red[(t >> 6) * 2] = s; red[(t >> 6) * 2 + 1] = sq; }
    __syncthreads();
    s = red[0] + red[2] + red[4] + red[6];
    sq = red[1] + red[3] + red[5] + red[7];
    float mu = s * (1.f / 512.f);
    float rstd = rsqrtf(sq * (1.f / 512.f) - mu * mu + EPSV);
    float o0 = (v.x - mu) * rstd * pgln[c] + pgln[512 + c];
    float o1 = (v.y - mu) * rstd * pgln[c + 1] + pgln[512 + c + 1];
    size_t row = (size_t)(b * NTOK + pI);
    jt[row * 512 + c] = o0;
    jt[row * 512 + c + 1] = o1;
    float s2 = o0 + o1, sq2 = o0 * o0 + o1 * o1;
    #pragma unroll
    for (int off = 1; off < 64; off <<= 1) { s2 += __shfl_xor(s2, off); sq2 += __shfl_xor(sq2, off); }
    if ((t & 63) == 0) { red[8 + (t >> 6) * 2] = s2; red[9 + (t >> 6) * 2] = sq2; }
    __syncthreads();
    s2 = red[8] + red[10] + red[12] + red[14];
    sq2 = red[9] + red[11] + red[13] + red[15];
    float mu2 = s2 * (1.f / 512.f);
    float rstd2 = rsqrtf(sq2 * (1.f / 512.f) - mu2 * mu2 + EPSV);
    xb[row * 512 + c]     = f2bf((o0 - mu2) * rstd2 * ln1[c] + ln1[512 + c]);
    xb[row * 512 + c + 1] = f2bf((o1 - mu2) * rstd2 * ln1[c + 1] + ln1[512 + c + 1]);
  } else {
    int idx = bx - 160;
    int b = idx >> 6, row0 = (idx & 63) * 16;
    int l = t & 63, w = t >> 6;
    bf16x8 wv = *(const bf16x8*)(gpw + l * 8);
    float wf[8];
    #pragma unroll
    for (int j = 0; j < 8; ++j) wf[j] = bf2f((ushort)wv[j]);
    float bias0 = b0[0];
    #pragma unroll
    for (int rr = 0; rr < 4; ++rr) {
      int hw = row0 + w * 4 + rr;
      bf16x8 xv = *(const bf16x8*)(dwT2 + ((size_t)(b * HWP + hw)) * CH + l * 8);
      float s = 0.0f;
      #pragma unroll
      for (int j = 0; j < 8; ++j) s += wf[j] * bf2f((ushort)xv[j]);
      #pragma unroll
      for (int off = 1; off < 64; off <<= 1) s += __shfl_xor(s, off);
      if (l == 0) {
        float sf = s + bias0;
        jdv[b * NTP + NPRM + hw] = sf;
        int y = hw >> 5, xx = hw & 31;
        int rg = (y >> 4) * 4 + (xx >> 3);
        atomicAdd(&jdv[b * NTP + rg], sf * (1.0f / 128.0f));
      }
    }
  }
}

// ---------------- row LayerNorm -> bf16 (ln2) ----------------
__global__ __launch_bounds__(128) void ln_rows_bf(
    const float* __restrict__ in, const float* __restrict__ lnp, ushort* __restrict__ out)
{
  int row = blockIdx.x;
  float4 val = ((const float4*)(in + (size_t)row * CH))[threadIdx.x];
  float sum = val.x + val.y + val.z + val.w;
  float sq = val.x * val.x + val.y * val.y + val.z * val.z + val.w * val.w;
  #pragma unroll
  for (int off = 1; off < 64; off <<= 1) { sum += __shfl_xor(sum, off); sq += __shfl_xor(sq, off); }
  __shared__ float s2[4];
  if ((threadIdx.x & 63) == 0) { s2[(threadIdx.x >> 6) * 2] = sum; s2[(threadIdx.x >> 6) * 2 + 1] = sq; }
  __syncthreads();
  sum = s2[0] + s2[2]; sq = s2[1] + s2[3];
  float mu = sum * (1.0f / 512.0f);
  float var = sq * (1.0f / 512.0f) - mu * mu;
  float rstd = rsqrtf(var + EPSV);
  int c = threadIdx.x * 4;
  ushort4 o;
  o.x = f2bf((val.x - mu) * rstd * lnp[c] + lnp[CH + c]);
  o.y = f2bf((val.y - mu) * rstd * lnp[c + 1] + lnp[CH + c + 1]);
  o.z = f2bf((val.z - mu) * rstd * lnp[c + 2] + lnp[CH + c + 2]);
  o.w = f2bf((val.w - mu) * rstd * lnp[c + 3] + lnp[CH + c + 3]);
  *(ushort4*)(out + (size_t)row * CH + c) = o;
}

// -------- dwt for out_proj: reads token-major jt --------
__global__ __launch_bounds__(256) void dwt_op(
    const float* __restrict__ jt, const float* __restrict__ w9p,
    const float* __restrict__ bn, ushort* __restrict__ outT)
{
  __shared__ float Tt[3][32][33];
  const int y = blockIdx.x;
  const int c0 = blockIdx.y * 32;
  const int b = blockIdx.z;
  const int tx = threadIdx.x, ty = threadIdx.y;
  #pragma unroll
  for (int ry = 0; ry < 3; ++ry) {
    int yy = y - 1 + ry;
    bool ok = (unsigned)yy < 32u;
    #pragma unroll
    for (int it = 0; it < 4; ++it) {
      int px = ty + it * 8;
      float v = ok ? jt[((size_t)(b * NTOK + NPRM + yy * 32 + px)) * 512 + c0 + tx] : 0.0f;
      Tt[ry][px][tx] = v;
    }
  }
  __syncthreads();
  int c = c0 + tx;
  float w9[9];
  #pragma unroll
  for (int k = 0; k < 9; ++k) w9[k] = w9p[c * 9 + k];
  float g = bn[c], be = bn[CH + c], mm = bn[2 * CH + c], vv = bn[3 * CH + c];
  float s = g * rsqrtf(vv + EPSV);
  float sh = be - mm * s;
  #pragma unroll
  for (int it = 0; it < 4; ++it) {
    int px = ty + it * 8;
    float acc = 0.0f;
    #pragma unroll
    for (int dy = 0; dy < 3; ++dy) {
      #pragma unroll
      for (int dx = 0; dx < 3; ++dx) {
        int xx = px + dx - 1;
        if ((unsigned)xx < 32u) acc += Tt[dy][xx][tx] * w9[dy * 3 + dx];
      }
    }
    outT[((size_t)(b * HWP + y * 32 + px)) * CH + c] = f2bf(gelu_f(acc * s + sh));
  }
}

// ---------------- MFMA flash attention: 8 waves, 128 q-rows, coalesced swizzled staging ----------------
__device__ __forceinline__ void tok_coord(int idx, float& y, float& x)
{
  if (idx < NPRM) { y = (float)(idx >> 2); x = (float)(idx & 3) * (1.0f / 3.0f); }
  else { int t = idx - NPRM; y = (float)(t >> 5) * (1.0f / 31.0f); x = (float)(t & 31) * (1.0f / 31.0f); }
}

__global__ __launch_bounds__(512) void attn_mfma4(
    const ushort* __restrict__ qh, const ushort* __restrict__ kh,
    const ushort* __restrict__ vT, const float* __restrict__ jd,
    const float* __restrict__ gw, ushort* __restrict__ ao)
{
  __shared__ ushort sK[8192], sV[8192];   // 2 buffers x [64 rows][64 ush] each, XOR-swizzled
  __shared__ ushort Pl[8][16][72];
  const int t = threadIdx.x, l = t & 63, w = t >> 6;
  const int h = blockIdx.y, b = blockIdx.z;
  const int i0 = blockIdx.x * 128 + w * 16;
  const ushort* Q = qh + (size_t)(b * 8 + h) * NTP * 64;
  const ushort* K = kh + (size_t)(b * 8 + h) * NTP * 64;
  const ushort* V = vT + (size_t)(b * 8 + h) * 64 * NTP;
  const float* jdb = jd + b * NTP;
  const float decay = logf(1.0f - exp2f(-1.0f - 0.5f * (float)h)) * LOG2E;
  const float g0 = gw[0] * decay, g1 = gw[1] * decay;

  bf16x8 qf0 = *(const bf16x8*)(Q + (size_t)(i0 + (l & 15)) * 64 + (l >> 4) * 8);
  bf16x8 qf1 = *(const bf16x8*)(Q + (size_t)(i0 + (l & 15)) * 64 + 32 + (l >> 4) * 8);

  bf16x8 ones;
  {
    short ov = (short)((l & 15) == 0 ? 0x3F80 : 0);
    #pragma unroll
    for (int j = 0; j < 8; ++j) ones[j] = ov;
  }

  f32x4 of[4], lacc;
  { f32x4 z = {0.f, 0.f, 0.f, 0.f};
    #pragma unroll
    for (int d = 0; d < 4; ++d) of[d] = z;
    lacc = z; }

  // coalesced stage: wave w stages rows w*8..w*8+7 of each tile; 8 lanes/row,
  // chunk (l&7)^(row&7) -> LDS[r][c] holds global chunk c^(r&7)
#define ASTAGE(buf, j0s) { \
    int srow = w * 8 + (l >> 3); \
    int schk = (l & 7) ^ (srow & 7); \
    gl16(K + (size_t)((j0s) + srow) * 64 + schk * 8, sK + (buf) * 4096 + w * 512); \
    gl16(V + (size_t)srow * NTP + (j0s) + schk * 8, sV + (buf) * 4096 + w * 512); }

  ASTAGE(0, 0)
  __syncthreads();

  float yi[4], xi[4], jdi[4];
  #pragma unroll
  for (int r = 0; r < 4; ++r) {
    int i = i0 + (l >> 4) * 4 + r;
    tok_coord(i, yi[r], xi[r]);
    jdi[r] = jdb[i];
  }

  const int NJT = 17;
  for (int jti = 0; jti < NJT; ++jti) {
    const int j0 = jti * 64;
    if (jti + 1 < NJT) ASTAGE((jti + 1) & 1, j0 + 64)
    const ushort* bK = sK + (jti & 1) * 4096;
    const ushort* bV = sV + (jti & 1) * 4096;

    f32x4 sfr[4];
    __builtin_amdgcn_s_setprio(1);
    #pragma unroll
    for (int jf = 0; jf < 4; ++jf) {
      int kr = jf * 16 + (l & 15);
      bf16x8 k0 = *(const bf16x8*)(bK + kr * 64 + (((l >> 4) ^ (kr & 7)) * 8));
      bf16x8 k1 = *(const bf16x8*)(bK + kr * 64 + (((4 + (l >> 4)) ^ (kr & 7)) * 8));
      f32x4 z = {0.f, 0.f, 0.f, 0.f};
      z = __builtin_amdgcn_mfma_f32_16x16x32_bf16(qf0, k0, z, 0, 0, 0);
      z = __builtin_amdgcn_mfma_f32_16x16x32_bf16(qf1, k1, z, 0, 0, 0);
      sfr[jf] = z;
    }
    __builtin_amdgcn_s_setprio(0);
    #pragma unroll
    for (int jf = 0; jf < 4; ++jf) {
      int jj = j0 + jf * 16 + (l & 15);
      float yj, xj;
      tok_coord(jj, yj, xj);
      float jdj = jdb[jj];
      bool valid = jj < NTOK;
      #pragma unroll
      for (int r = 0; r < 4; ++r) {
        float bias = g0 * (fabsf(yi[r] - yj) + fabsf(xi[r] - xj)) + g1 * fabsf(jdi[r] - jdj);
        float p = valid ? exp2f(sfr[jf][r] + bias - 4.0f) : 0.0f;
        Pl[w][(l >> 4) * 4 + r][jf * 16 + (l & 15)] = f2bf(p);
      }
    }
    asm volatile("s_waitcnt lgkmcnt(0)" ::: "memory");
    bf16x8 pa0 = *(const bf16x8*)&Pl[w][l & 15][(l >> 4) * 8];
    bf16x8 pa1 = *(const bf16x8*)&Pl[w][l & 15][32 + (l >> 4) * 8];
    __builtin_amdgcn_s_setprio(1);
    #pragma unroll
    for (int df = 0; df < 4; ++df) {
      int vr = df * 16 + (l & 15);
      bf16x8 v0 = *(const bf16x8*)(bV + vr * 64 + (((l >> 4) ^ (vr & 7)) * 8));
      bf16x8 v1 = *(const bf16x8*)(bV + vr * 64 + (((4 + (l >> 4)) ^ (vr & 7)) * 8));
      of[df] = __builtin_amdgcn_mfma_f32_16x16x32_bf16(pa0, v0, of[df], 0, 0, 0);
      of[df] = __builtin_amdgcn_mfma_f32_16x16x32_bf16(pa1, v1, of[df], 0, 0, 0);
    }
    lacc = __builtin_amdgcn_mfma_f32_16x16x32_bf16(pa0, ones, lacc, 0, 0, 0);
    lacc = __builtin_amdgcn_mfma_f32_16x16x32_bf16(pa1, ones, lacc, 0, 0, 0);
    __builtin_amdgcn_s_setprio(0);
    __syncthreads();
  }
  #pragma unroll
  for (int r = 0; r < 4; ++r) {
    int i = i0 + (l >> 4) * 4 + r;
    float lsum = __shfl(lacc[r], (l & 48), 64);
    if (i < NTOK) {
      float inv = 1.0f / lsum;
      #pragma unroll
      for (int df = 0; df < 4; ++df)
        ao[((size_t)(b * NTOK + i)) * 512 + h * 64 + df * 16 + (l & 15)] = f2bf(of[df][r] * inv);
    }
  }
}

// ---------------- host ----------------
extern "C" void kernel_launch(void* const* d_in, const int* in_sizes, int n_in,
                              void* d_out, int out_size, void* d_ws, size_t ws_size,
                              hipStream_t stream)
{
  const float* fused = (const float*)d_in[0];
  const float* depth = (const float*)d_in[1];
  const float* pg_dw_w = (const float*)d_in[2];
  const float* pg_bn1 = (const float*)d_in[3];
  const float* pg_pw_w = (const float*)d_in[4];
  const float* pg_bn2 = (const float*)d_in[5];
  const float* prompt_embed = (const float*)d_in[6];
  const float* pg_ln = (const float*)d_in[7];
  const float* gp_dw_w = (const float*)d_in[8];
  const float* gp_bn = (const float*)d_in[9];
  const float* gp_pw_w = (const float*)d_in[10];
  const float* gp_pw_b = (const float*)d_in[11];
  const float* gp_weight = (const float*)d_in[12];
  const float* ln1 = (const float*)d_in[13];
  const float* wq = (const float*)d_in[14];
  const float* wk = (const float*)d_in[15];
  const float* wv = (const float*)d_in[16];
  const float* wo = (const float*)d_in[17];
  const float* ln2 = (const float*)d_in[18];
  const float* mlp_w1 = (const float*)d_in[19];
  const float* mlp_b1 = (const float*)d_in[20];
  const float* mlp_w2 = (const float*)d_in[21];
  const float* mlp_b2 = (const float*)d_in[22];
  const float* op_dw_w = (const float*)d_in[23];
  const float* op_bn1 = (const float*)d_in[24];
  const float* op_pw_w = (const float*)d_in[25];
  const float* op_bn2 = (const float*)d_in[26];
  float* out = (float*)d_out;

  char* p = (char*)d_ws;
  auto alloc = [&](size_t bytes) { char* r = p; p += (bytes + 1023) & ~(size_t)1023; return r; };
  float*  jdv   = (float*) alloc((size_t)BB * NTP * 4);
  float*  ppool = (float*) alloc((size_t)BB * 8 * CH * 4);
  float*  jt    = (float*) alloc((size_t)MTOK * 512 * 4);
  ushort* xb    = (ushort*)alloc((size_t)MPAD * 512 * 2);
  ushort* hb    = (ushort*)alloc((size_t)MPAD * 1024 * 2);
  ushort* ao    = (ushort*)alloc((size_t)MPAD * 512 * 2);
  ushort* qhB   = (ushort*)alloc((size_t)32 * NTP * 64 * 2);
  ushort* khB   = (ushort*)alloc((size_t)32 * NTP * 64 * 2);
  ushort* vhB   = (ushort*)alloc((size_t)32 * NTP * 64 * 2);
  ushort* vTB   = (ushort*)alloc((size_t)32 * NTP * 64 * 2);
  ushort* dwT1  = (ushort*)alloc((size_t)BB * HWP * CH * 2);
  ushort* dwT2  = (ushort*)alloc((size_t)BB * HWP * CH * 2);
  ushort* wbf   = (ushort*)alloc((size_t)2621952 * 2);

  ushort* wqkv_bf = wbf;
  ushort* wo_bf   = wbf + 786432;
  ushort* w1_bf   = wbf + 1048576;
  ushort* w2_bf   = wbf + 1572864;
  ushort* pgw_bf  = wbf + 2097152;
  ushort* opw_bf  = wbf + 2359296;
  ushort* gpw_bf  = wbf + 2621440;

  hipMemsetAsync(jdv, 0, (size_t)BB * NTP * 4, stream);
  hipMemsetAsync(ppool, 0, (size_t)BB * 8 * CH * 4, stream);

  hipLaunchKernelGGL(convw, dim3(2048), dim3(256), 0, stream,
                     wq, wk, wv, wo, mlp_w1, mlp_w2, pg_pw_w, op_pw_w, gp_pw_w, wbf);

  hipLaunchKernelGGL(dwt_dual, dim3(32, 16, BB), dim3(32, 8), 0, stream,
                     depth, pg_dw_w, pg_bn1, gp_dw_w, gp_bn, dwT1, dwT2);
  hipLaunchKernelGGL(g_pw_pool, dim3(16, 8, BB), dim3(256), 0, stream, pgw_bf, dwT1, pg_bn2, ppool);
  hipLaunchKernelGGL(combo_mid, dim3(416), dim3(256), 0, stream,
                     fused, ppool, prompt_embed, pg_ln, ln1, jt, xb, dwT2, gpw_bf, gp_pw_b, jdv);
  hipLaunchKernelGGL(g_qkv, dim3(24, 65), dim3(256), 0, stream, xb, wqkv_bf, qhB, khB, vhB);
  hipLaunchKernelGGL(transp_v, dim3(36, 2, 32), dim3(32, 8), 0, stream, vhB, vTB);
  hipLaunchKernelGGL(attn_mfma4, dim3(9, 8, BB), dim3(512), 0, stream, qhB, khB, vTB, jdv, gp_weight, ao);
  hipLaunchKernelGGL(g_res<2>, dim3(8, 65), dim3(256), 0, stream, ao, wo_bf, jt, (const float*)nullptr);
  hipLaunchKernelGGL(ln_rows_bf, dim3(MTOK), dim3(128), 0, stream, jt, ln2, xb);
  hipLaunchKernelGGL(g_gelu, dim3(16, 65), dim3(256), 0, stream, xb, w1_bf, mlp_b1, hb);
  hipLaunchKernelGGL(g_res<4>, dim3(8, 65), dim3(256), 0, stream, hb, w2_bf, jt, mlp_b2);
  hipLaunchKernelGGL(dwt_op, dim3(32, 16, BB), dim3(32, 8), 0, stream, jt, op_dw_w, op_bn1, dwT1);
  hipLaunchKernelGGL(g_pw_res, dim3(16, 8, BB), dim3(256), 0, stream, opw_bf, dwT1, op_bn2, fused, out);
}